// Round 14
// baseline (552.180 us; speedup 1.0000x reference)
//
#include <hip/hip_runtime.h>
#include <hip/hip_bf16.h>

#define LEAKY 0.2f
#define EPS_GN 1e-5f
#define PSH 9                    // 512 nodes per partition (P<=256, N<=131072)

typedef unsigned int uint;

// ---------------- bf16 helpers (storage only; compute fp32) ----------------

__device__ inline float4 bf4(uint lo, uint hi) {
    union { uint u; float f; } a, b, c, d;
    a.u = lo << 16; b.u = lo & 0xFFFF0000u;
    c.u = hi << 16; d.u = hi & 0xFFFF0000u;
    return make_float4(a.f, b.f, c.f, d.f);
}

__device__ inline uint pack_bf2(float lo, float hi) {
    union { float f; uint u; } x, y; x.f = lo; y.f = hi;
    uint ra = x.u + 0x7FFFu + ((x.u >> 16) & 1u);
    uint rb = y.u + 0x7FFFu + ((y.u >> 16) & 1u);
    return (ra >> 16) | (rb & 0xFFFF0000u);
}

__device__ inline unsigned short pack_bf1(float v) {
    union { float f; uint u; } q; q.f = v;
    return (unsigned short)((q.u + 0x7FFFu + ((q.u >> 16) & 1u)) >> 16);
}

// ---------------- CSR build ----------------

__global__ void zero_int_kernel(int* __restrict__ p, int n) {
    int i = blockIdx.x * blockDim.x + threadIdx.x;
    if (i < n) p[i] = 0;
}

__global__ void hist_kernel(const int* __restrict__ dst, int* __restrict__ deg, int E_, int Etot_) {
    int i = blockIdx.x * blockDim.x + threadIdx.x;
    if (i >= Etot_) return;
    int d = (i < E_) ? dst[i] : (i - E_);
    atomicAdd(&deg[d], 1);
}

__global__ void scan1_kernel(const int* __restrict__ deg, int* __restrict__ bsum, int nN) {
    __shared__ int sd[256];
    int i = blockIdx.x * 256 + threadIdx.x;
    sd[threadIdx.x] = (i < nN) ? deg[i] : 0;
    __syncthreads();
    for (int off = 128; off > 0; off >>= 1) {
        if (threadIdx.x < off) sd[threadIdx.x] += sd[threadIdx.x + off];
        __syncthreads();
    }
    if (threadIdx.x == 0) bsum[blockIdx.x] = sd[0];
}

// parallel scan over up to 512 block sums; also zeroes csr pad (16 ints)
__global__ void scan2_kernel(const int* __restrict__ bsum, int* __restrict__ bofs, int nb,
                             int* __restrict__ rowstart, int nN, int* __restrict__ csr_pad) {
    __shared__ int sd[512];
    int tid = threadIdx.x;
    int v = (tid < nb) ? bsum[tid] : 0;
    sd[tid] = v;
    __syncthreads();
    for (int off = 1; off < 512; off <<= 1) {
        int t = (tid >= off) ? sd[tid - off] : 0;
        __syncthreads();
        sd[tid] += t;
        __syncthreads();
    }
    if (tid < nb) bofs[tid] = sd[tid] - v;
    if (tid == 511) rowstart[nN] = sd[511];
    if (tid < 16) csr_pad[tid] = 0;
}

__global__ void scan3_kernel(const int* __restrict__ deg, const int* __restrict__ bofs,
                             int* __restrict__ rowstart, int nN) {
    __shared__ int sd[256];
    int i = blockIdx.x * 256 + threadIdx.x;
    int v = (i < nN) ? deg[i] : 0;
    sd[threadIdx.x] = v;
    __syncthreads();
    for (int off = 1; off < 256; off <<= 1) {
        int t = (threadIdx.x >= off) ? sd[threadIdx.x - off] : 0;
        __syncthreads();
        sd[threadIdx.x] += t;
        __syncthreads();
    }
    if (i < nN) rowstart[i] = bofs[blockIdx.x] + sd[threadIdx.x] - v;
}

__global__ void init_gcur_kernel(const int* __restrict__ rowstart, int* __restrict__ gcur,
                                 int P, int nN) {
    int p = blockIdx.x * blockDim.x + threadIdx.x;
    if (p > P) return;
    int node = p << PSH;
    if (node > nN) node = nN;
    gcur[p] = rowstart[node];
}

// Phase A: block-aggregated partition scatter. rec = src | dst_local<<17.
__global__ void partA_kernel(const int* __restrict__ srcs, const int* __restrict__ dsts,
                             int* __restrict__ gcur, uint* __restrict__ ebuf,
                             int E_, int Etot_) {
    __shared__ int hist[256], base_s[256], lcur[256];
    int tid = threadIdx.x;
    hist[tid] = 0; lcur[tid] = 0;
    __syncthreads();
    int i0 = blockIdx.x * 2048 + tid;
    uint rec[8]; int pp[8];
#pragma unroll
    for (int k = 0; k < 8; ++k) {
        int i = i0 + k * 256;
        pp[k] = -1;
        if (i < Etot_) {
            int s, d;
            if (i < E_) { s = srcs[i]; d = dsts[i]; } else { s = i - E_; d = s; }
            int p = d >> PSH;
            pp[k] = p;
            rec[k] = (uint)s | ((uint)(d & ((1 << PSH) - 1)) << 17);
            atomicAdd(&hist[p], 1);
        }
    }
    __syncthreads();
    int h = hist[tid];
    if (h > 0) base_s[tid] = atomicAdd(&gcur[tid], h);
    __syncthreads();
#pragma unroll
    for (int k = 0; k < 8; ++k) {
        if (pp[k] >= 0) {
            int pos = base_s[pp[k]] + atomicAdd(&lcur[pp[k]], 1);
            ebuf[pos] = rec[k];
        }
    }
}

// Phase B: one block per partition, exclusive LDS cursors, dense csr writes.
__global__ void partB_kernel(const uint* __restrict__ ebuf, const int* __restrict__ rowstart,
                             int* __restrict__ csr, int nN) {
    __shared__ int lcur[512];
    int tid = threadIdx.x;
    lcur[tid] = 0; lcur[tid + 256] = 0;
    __syncthreads();
    int n0 = blockIdx.x << PSH;
    int n1 = n0 + (1 << PSH);
    if (n1 > nN) n1 = nN;
    int lo = rowstart[n0], hi = rowstart[n1];
    const int* rs = rowstart + n0;
    for (int i = lo + tid; i < hi; i += 256) {
        uint v = ebuf[i];
        int dl = (int)(v >> 17);
        int pos = rs[dl] + atomicAdd(&lcur[dl], 1);
        csr[pos] = (int)(v & 0x1FFFFu);
    }
}

__global__ void goff_kernel(const int* __restrict__ batch, int* __restrict__ goff, int nN, int nG) {
    int g = blockIdx.x * blockDim.x + threadIdx.x;
    if (g > nG) return;
    if (g == nG) { goff[g] = nN; return; }
    int lo = 0, hi = nN;
    while (lo < hi) { int mid = (lo + hi) >> 1; if (batch[mid] < g) lo = mid + 1; else hi = mid; }
    goff[g] = lo;
}

// ---------------- GEMM variant A (D=64 layers): fused [Wl|Wr] (128 cols), global-x ----------------

template <bool NORM>
__global__ __launch_bounds__(256, 4)
void gemm2_gxf_kernel(const float* __restrict__ x, const float* __restrict__ Wl,
                      const float* __restrict__ Wr, unsigned short* __restrict__ xl,
                      unsigned short* __restrict__ xr, int nN,
                      const float* __restrict__ param, const int* __restrict__ batch) {
    constexpr int WROW = 136;
    __shared__ float w_s[64 * WROW];
    int tid = threadIdx.x;
    int ng = tid >> 3, cc = tid & 7;
    int nbase = blockIdx.x * 64 + ng * 2;

    const float* xp[2];
    const float* pp[2];
    bool val[2];
#pragma unroll
    for (int r = 0; r < 2; ++r) {
        int n = nbase + r;
        val[r] = n < nN;
        int nc = val[r] ? n : 0;
        xp[r] = x + (size_t)nc * 64;
        if constexpr (NORM) pp[r] = param + (size_t)batch[nc] * 128;
    }

    for (int i = tid; i < 64 * 128; i += 256) {
        int r = i >> 7, c = i & 127;
        float wv = (c < 64) ? Wl[r * 64 + c] : Wr[r * 64 + (c - 64)];
        w_s[r * WROW + (c >> 4) * 17 + (c & 15)] = wv;
    }
    __syncthreads();

    float acc[2][16];
#pragma unroll
    for (int r = 0; r < 2; ++r)
#pragma unroll
        for (int j = 0; j < 16; ++j) acc[r][j] = 0.f;
    const float* wp = &w_s[cc * 17];

    for (int kc = 0; kc < 8; ++kc) {
        float xv[2][8];
#pragma unroll
        for (int r = 0; r < 2; ++r) {
            const float4* xf = (const float4*)(xp[r]) + kc * 2;
            float4 a = xf[0], b = xf[1];
            float t0 = a.x, t1 = a.y, t2 = a.z, t3 = a.w;
            float t4 = b.x, t5 = b.y, t6 = b.z, t7 = b.w;
            if constexpr (NORM) {
                const float4* scf = (const float4*)(pp[r]) + kc * 2;
                const float4* shf = (const float4*)(pp[r] + 64) + kc * 2;
                float4 s0 = scf[0], s1 = scf[1];
                float4 h0 = shf[0], h1 = shf[1];
                t0 = fmaxf(fmaf(s0.x, t0, h0.x), 0.f);
                t1 = fmaxf(fmaf(s0.y, t1, h0.y), 0.f);
                t2 = fmaxf(fmaf(s0.z, t2, h0.z), 0.f);
                t3 = fmaxf(fmaf(s0.w, t3, h0.w), 0.f);
                t4 = fmaxf(fmaf(s1.x, t4, h1.x), 0.f);
                t5 = fmaxf(fmaf(s1.y, t5, h1.y), 0.f);
                t6 = fmaxf(fmaf(s1.z, t6, h1.z), 0.f);
                t7 = fmaxf(fmaf(s1.w, t7, h1.w), 0.f);
            }
            xv[r][0] = t0; xv[r][1] = t1; xv[r][2] = t2; xv[r][3] = t3;
            xv[r][4] = t4; xv[r][5] = t5; xv[r][6] = t6; xv[r][7] = t7;
        }
#pragma unroll
        for (int kk = 0; kk < 8; ++kk) {
            const float* wrow = wp + (kc * 8 + kk) * WROW;
#pragma unroll
            for (int j = 0; j < 16; ++j) {
                float wv = wrow[j];
                acc[0][j] = fmaf(xv[0][kk], wv, acc[0][j]);
                acc[1][j] = fmaf(xv[1][kk], wv, acc[1][j]);
            }
        }
    }
#pragma unroll
    for (int r = 0; r < 2; ++r) {
        if (val[r]) {
            unsigned short* op = (cc < 4) ? (xl + (size_t)(nbase + r) * 64 + cc * 16)
                                         : (xr + (size_t)(nbase + r) * 64 + (cc - 4) * 16);
            uint4* dst = (uint4*)op;
            dst[0] = make_uint4(pack_bf2(acc[r][0], acc[r][1]), pack_bf2(acc[r][2], acc[r][3]),
                                pack_bf2(acc[r][4], acc[r][5]), pack_bf2(acc[r][6], acc[r][7]));
            dst[1] = make_uint4(pack_bf2(acc[r][8], acc[r][9]), pack_bf2(acc[r][10], acc[r][11]),
                                pack_bf2(acc[r][12], acc[r][13]), pack_bf2(acc[r][14], acc[r][15]));
        }
    }
}

// ---------------- GEMM variant B (D=128 layer): RN=4, transposed bf16 x in LDS ----------------

template <bool NORM>
__global__ __launch_bounds__(256, 3)
void gemm2_sx4_kernel(const float* __restrict__ x, const float* __restrict__ Wl,
                      const float* __restrict__ Wr, unsigned short* __restrict__ xl,
                      unsigned short* __restrict__ xr, int nN,
                      const float* __restrict__ param, const int* __restrict__ batch) {
    constexpr int WROW = 136;               // 128 + 8 swizzle stride
    __shared__ float w_s[64 * WROW];        // 34.8 KB
    __shared__ unsigned short xb_s[64 * 128]; // 16 KB, [k][node]
    int tid = threadIdx.x;
    int node0 = blockIdx.x * 128;

    {
        int nl = tid & 127;
        int c0 = (tid >> 7) * 32;
        int n = node0 + nl;
        bool v = n < nN;
        int nc = v ? n : 0;
        const float* xrow = x + (size_t)nc * 64 + c0;
        const float* scp = nullptr; const float* shp = nullptr;
        if constexpr (NORM) {
            int g = batch[nc];
            scp = param + (size_t)g * 128 + c0;
            shp = param + (size_t)g * 128 + 64 + c0;
        }
#pragma unroll 8
        for (int j = 0; j < 32; ++j) {
            float t = v ? xrow[j] : 0.f;
            if constexpr (NORM) t = fmaxf(fmaf(scp[j], t, shp[j]), 0.f);
            xb_s[(c0 + j) * 128 + nl] = pack_bf1(t);
        }
    }

    int ng = tid >> 3, cc = tid & 7;
    int nbase = node0 + ng * 4;
    float acc[4][16];

    for (int m = 0; m < 2; ++m) {
        const float* W = (m == 0) ? Wl : Wr;
        unsigned short* outp = (m == 0) ? xl : xr;
        __syncthreads();   // xb_s ready (m=0) / previous w_s readers done (m=1)
        for (int i = tid; i < 64 * 128; i += 256) {
            int r = i >> 7, c = i & 127;
            w_s[r * WROW + (c >> 4) * 17 + (c & 15)] = W[i];
        }
        __syncthreads();
#pragma unroll
        for (int r = 0; r < 4; ++r)
#pragma unroll
            for (int j = 0; j < 16; ++j) acc[r][j] = 0.f;
        const float* wp = &w_s[cc * 17];
#pragma unroll 4
        for (int k = 0; k < 64; ++k) {
            uint2 u = ((const uint2*)xb_s)[k * 32 + ng];
            union { uint u; float f; } q0, q1, q2, q3;
            q0.u = u.x << 16; q1.u = u.x & 0xFFFF0000u;
            q2.u = u.y << 16; q3.u = u.y & 0xFFFF0000u;
            const float* wrow = wp + k * WROW;
#pragma unroll
            for (int j = 0; j < 16; ++j) {
                float wv = wrow[j];
                acc[0][j] = fmaf(q0.f, wv, acc[0][j]);
                acc[1][j] = fmaf(q1.f, wv, acc[1][j]);
                acc[2][j] = fmaf(q2.f, wv, acc[2][j]);
                acc[3][j] = fmaf(q3.f, wv, acc[3][j]);
            }
        }
#pragma unroll
        for (int r = 0; r < 4; ++r) {
            if (nbase + r < nN) {
                uint4* dst = (uint4*)(outp + (size_t)(nbase + r) * 128 + cc * 16);
                dst[0] = make_uint4(pack_bf2(acc[r][0], acc[r][1]), pack_bf2(acc[r][2], acc[r][3]),
                                    pack_bf2(acc[r][4], acc[r][5]), pack_bf2(acc[r][6], acc[r][7]));
                dst[1] = make_uint4(pack_bf2(acc[r][8], acc[r][9]), pack_bf2(acc[r][10], acc[r][11]),
                                    pack_bf2(acc[r][12], acc[r][13]), pack_bf2(acc[r][14], acc[r][15]));
            }
        }
    }
}

// ---------------- Aggregate layer 1-2: D=64, H=4, C=16, concat ----------------

__global__ void agg64_kernel(const unsigned short* __restrict__ xl, const unsigned short* __restrict__ xr,
                             const int* __restrict__ rowstart, const int* __restrict__ csr,
                             const float* __restrict__ att, const float* __restrict__ bias,
                             float* __restrict__ out, int nN) {
    int wid = (blockIdx.x * blockDim.x + threadIdx.x) >> 6;
    int lane = threadIdx.x & 63;
    if (wid >= nN) return;
    int c8 = lane & 7;
    int sg = lane >> 3;
    const uint4* xl4 = (const uint4*)xl;
    const float LOG2E = 1.4426950408889634f;
    float4 attA = ((const float4*)att)[c8 * 2];
    float4 attB = ((const float4*)att)[c8 * 2 + 1];
    attA.x *= LOG2E; attA.y *= LOG2E; attA.z *= LOG2E; attA.w *= LOG2E;
    attB.x *= LOG2E; attB.y *= LOG2E; attB.z *= LOG2E; attB.w *= LOG2E;
    uint4 xru = ((const uint4*)xr)[(size_t)wid * 8 + c8];
    float4 xrA = bf4(xru.x, xru.y), xrB = bf4(xru.z, xru.w);
    int rs = rowstart[wid], re = rowstart[wid + 1];
    int nIt = (re - rs + 7) >> 3;
    float den = 0.f;
    float4 accA = make_float4(0.f, 0.f, 0.f, 0.f);
    float4 accB = make_float4(0.f, 0.f, 0.f, 0.f);
    int i = rs + sg;
    int s = csr[i];
    uint4 xv = xl4[(size_t)s * 8 + c8];
    for (int it = 0; it < nIt; ++it) {
        float4 curA = bf4(xv.x, xv.y), curB = bf4(xv.z, xv.w);
        bool vv = i < re;
        i += 8;
        s = csr[i];
        xv = xl4[(size_t)s * 8 + c8];
        float4 mA, mB;
        mA.x = curA.x + xrA.x; mA.y = curA.y + xrA.y;
        mA.z = curA.z + xrA.z; mA.w = curA.w + xrA.w;
        mB.x = curB.x + xrB.x; mB.y = curB.y + xrB.y;
        mB.z = curB.z + xrB.z; mB.w = curB.w + xrB.w;
        mA.x = fmaxf(mA.x, LEAKY * mA.x); mA.y = fmaxf(mA.y, LEAKY * mA.y);
        mA.z = fmaxf(mA.z, LEAKY * mA.z); mA.w = fmaxf(mA.w, LEAKY * mA.w);
        mB.x = fmaxf(mB.x, LEAKY * mB.x); mB.y = fmaxf(mB.y, LEAKY * mB.y);
        mB.z = fmaxf(mB.z, LEAKY * mB.z); mB.w = fmaxf(mB.w, LEAKY * mB.w);
        float p = mA.x * attA.x;
        p = fmaf(mA.y, attA.y, p); p = fmaf(mA.z, attA.z, p); p = fmaf(mA.w, attA.w, p);
        p = fmaf(mB.x, attB.x, p); p = fmaf(mB.y, attB.y, p);
        p = fmaf(mB.z, attB.z, p); p = fmaf(mB.w, attB.w, p);
        p += __shfl_xor(p, 1);
        float w = vv ? exp2f(p) : 0.f;
        den += w;
        accA.x = fmaf(w, curA.x, accA.x); accA.y = fmaf(w, curA.y, accA.y);
        accA.z = fmaf(w, curA.z, accA.z); accA.w = fmaf(w, curA.w, accA.w);
        accB.x = fmaf(w, curB.x, accB.x); accB.y = fmaf(w, curB.y, accB.y);
        accB.z = fmaf(w, curB.z, accB.z); accB.w = fmaf(w, curB.w, accB.w);
    }
#pragma unroll
    for (int off = 8; off <= 32; off <<= 1) {
        den    += __shfl_xor(den, off);
        accA.x += __shfl_xor(accA.x, off); accA.y += __shfl_xor(accA.y, off);
        accA.z += __shfl_xor(accA.z, off); accA.w += __shfl_xor(accA.w, off);
        accB.x += __shfl_xor(accB.x, off); accB.y += __shfl_xor(accB.y, off);
        accB.z += __shfl_xor(accB.z, off); accB.w += __shfl_xor(accB.w, off);
    }
    if (lane < 8) {
        float4 bvA = ((const float4*)bias)[c8 * 2];
        float4 bvB = ((const float4*)bias)[c8 * 2 + 1];
        float inv = 1.f / den;
        float4 rA, rB;
        rA.x = fmaf(accA.x, inv, bvA.x); rA.y = fmaf(accA.y, inv, bvA.y);
        rA.z = fmaf(accA.z, inv, bvA.z); rA.w = fmaf(accA.w, inv, bvA.w);
        rB.x = fmaf(accB.x, inv, bvB.x); rB.y = fmaf(accB.y, inv, bvB.y);
        rB.z = fmaf(accB.z, inv, bvB.z); rB.w = fmaf(accB.w, inv, bvB.w);
        ((float4*)out)[(size_t)wid * 16 + c8 * 2]     = rA;
        ((float4*)out)[(size_t)wid * 16 + c8 * 2 + 1] = rB;
    }
}

// ---------------- Aggregate layer 3: D=128, H=4, C=32, head-mean ----------------

__global__ void agg128_mean_kernel(const unsigned short* __restrict__ xl, const unsigned short* __restrict__ xr,
                                   const int* __restrict__ rowstart, const int* __restrict__ csr,
                                   const float* __restrict__ att, const float* __restrict__ bias,
                                   float* __restrict__ out, int nN) {
    int wid = (blockIdx.x * blockDim.x + threadIdx.x) >> 6;
    int lane = threadIdx.x & 63;
    if (wid >= nN) return;
    int c8 = lane & 15;
    int sg = lane >> 4;
    const uint4* xl4 = (const uint4*)xl;
    const float LOG2E = 1.4426950408889634f;
    float4 attA = ((const float4*)att)[c8 * 2];
    float4 attB = ((const float4*)att)[c8 * 2 + 1];
    attA.x *= LOG2E; attA.y *= LOG2E; attA.z *= LOG2E; attA.w *= LOG2E;
    attB.x *= LOG2E; attB.y *= LOG2E; attB.z *= LOG2E; attB.w *= LOG2E;
    uint4 xru = ((const uint4*)xr)[(size_t)wid * 16 + c8];
    float4 xrA = bf4(xru.x, xru.y), xrB = bf4(xru.z, xru.w);
    int rs = rowstart[wid], re = rowstart[wid + 1];
    int nIt = (re - rs + 3) >> 2;
    float den = 0.f;
    float4 accA = make_float4(0.f, 0.f, 0.f, 0.f);
    float4 accB = make_float4(0.f, 0.f, 0.f, 0.f);
    int i = rs + sg;
    int s = csr[i];
    uint4 xv = xl4[(size_t)s * 16 + c8];
    for (int it = 0; it < nIt; ++it) {
        float4 curA = bf4(xv.x, xv.y), curB = bf4(xv.z, xv.w);
        bool vv = i < re;
        i += 4;
        s = csr[i];
        xv = xl4[(size_t)s * 16 + c8];
        float4 mA, mB;
        mA.x = curA.x + xrA.x; mA.y = curA.y + xrA.y;
        mA.z = curA.z + xrA.z; mA.w = curA.w + xrA.w;
        mB.x = curB.x + xrB.x; mB.y = curB.y + xrB.y;
        mB.z = curB.z + xrB.z; mB.w = curB.w + xrB.w;
        mA.x = fmaxf(mA.x, LEAKY * mA.x); mA.y = fmaxf(mA.y, LEAKY * mA.y);
        mA.z = fmaxf(mA.z, LEAKY * mA.z); mA.w = fmaxf(mA.w, LEAKY * mA.w);
        mB.x = fmaxf(mB.x, LEAKY * mB.x); mB.y = fmaxf(mB.y, LEAKY * mB.y);
        mB.z = fmaxf(mB.z, LEAKY * mB.z); mB.w = fmaxf(mB.w, LEAKY * mB.w);
        float p = mA.x * attA.x;
        p = fmaf(mA.y, attA.y, p); p = fmaf(mA.z, attA.z, p); p = fmaf(mA.w, attA.w, p);
        p = fmaf(mB.x, attB.x, p); p = fmaf(mB.y, attB.y, p);
        p = fmaf(mB.z, attB.z, p); p = fmaf(mB.w, attB.w, p);
        p += __shfl_xor(p, 1);
        p += __shfl_xor(p, 2);
        float w = vv ? exp2f(p) : 0.f;
        den += w;
        accA.x = fmaf(w, curA.x, accA.x); accA.y = fmaf(w, curA.y, accA.y);
        accA.z = fmaf(w, curA.z, accA.z); accA.w = fmaf(w, curA.w, accA.w);
        accB.x = fmaf(w, curB.x, accB.x); accB.y = fmaf(w, curB.y, accB.y);
        accB.z = fmaf(w, curB.z, accB.z); accB.w = fmaf(w, curB.w, accB.w);
    }
#pragma unroll
    for (int off = 16; off <= 32; off <<= 1) {
        den    += __shfl_xor(den, off);
        accA.x += __shfl_xor(accA.x, off); accA.y += __shfl_xor(accA.y, off);
        accA.z += __shfl_xor(accA.z, off); accA.w += __shfl_xor(accA.w, off);
        accB.x += __shfl_xor(accB.x, off); accB.y += __shfl_xor(accB.y, off);
        accB.z += __shfl_xor(accB.z, off); accB.w += __shfl_xor(accB.w, off);
    }
    float inv = 1.f / den;
    float4 rA, rB;
    rA.x = accA.x * inv; rA.y = accA.y * inv; rA.z = accA.z * inv; rA.w = accA.w * inv;
    rB.x = accB.x * inv; rB.y = accB.y * inv; rB.z = accB.z * inv; rB.w = accB.w * inv;
#pragma unroll
    for (int off = 4; off <= 8; off <<= 1) {
        rA.x += __shfl_xor(rA.x, off); rA.y += __shfl_xor(rA.y, off);
        rA.z += __shfl_xor(rA.z, off); rA.w += __shfl_xor(rA.w, off);
        rB.x += __shfl_xor(rB.x, off); rB.y += __shfl_xor(rB.y, off);
        rB.z += __shfl_xor(rB.z, off); rB.w += __shfl_xor(rB.w, off);
    }
    if (lane < 4) {
        float4 bvA = ((const float4*)bias)[lane * 2];
        float4 bvB = ((const float4*)bias)[lane * 2 + 1];
        float4 oA, oB;
        oA.x = fmaf(rA.x, 0.25f, bvA.x); oA.y = fmaf(rA.y, 0.25f, bvA.y);
        oA.z = fmaf(rA.z, 0.25f, bvA.z); oA.w = fmaf(rA.w, 0.25f, bvA.w);
        oB.x = fmaf(rB.x, 0.25f, bvB.x); oB.y = fmaf(rB.y, 0.25f, bvB.y);
        oB.z = fmaf(rB.z, 0.25f, bvB.z); oB.w = fmaf(rB.w, 0.25f, bvB.w);
        ((float4*)out)[(size_t)wid * 8 + lane * 2]     = oA;
        ((float4*)out)[(size_t)wid * 8 + lane * 2 + 1] = oB;
    }
}

// ---------------- GraphNorm stats / finalize ----------------

template <int D>
__global__ void gnorm_stats_kernel(const float* __restrict__ in, const int* __restrict__ goff,
                                   float* __restrict__ stats, int SPLIT) {
    int g = blockIdx.x / SPLIT, part = blockIdx.x % SPLIT;
    int start = goff[g], end = goff[g + 1];
    constexpr int RPB = 256 / D;
    int tid = threadIdx.x;
    int c = tid % D, sub = tid / D;
    float s1 = 0.f, s2 = 0.f;
    for (int n = start + part * RPB + sub; n < end; n += SPLIT * RPB) {
        float v = in[(size_t)n * D + c];
        s1 += v; s2 += v * v;
    }
    __shared__ float l1[256], l2[256];
    l1[tid] = s1; l2[tid] = s2;
    __syncthreads();
    if (tid < D) {
        for (int s = 1; s < RPB; ++s) { s1 += l1[s * D + tid]; s2 += l2[s * D + tid]; }
        atomicAdd(&stats[(size_t)g * 2 * D + tid], s1);
        atomicAdd(&stats[(size_t)g * 2 * D + D + tid], s2);
    }
}

template <int D>
__global__ void gnorm_finalize_kernel(const float* __restrict__ stats, const int* __restrict__ goff,
                                      const float* __restrict__ w, const float* __restrict__ b,
                                      const float* __restrict__ a, float* __restrict__ param) {
    int g = blockIdx.x, c = threadIdx.x;
    if (c >= D) return;
    int cn = goff[g + 1] - goff[g];
    float cnt = (float)(cn > 1 ? cn : 1);
    float S1 = stats[(size_t)g * 2 * D + c], S2 = stats[(size_t)g * 2 * D + D + c];
    float mu = S1 / cnt;
    float am = a[c] * mu;
    float var = S2 / cnt - 2.f * am * mu + am * am;
    float sc = w[c] * rsqrtf(var + EPS_GN);
    param[(size_t)g * 2 * D + c] = sc;
    param[(size_t)g * 2 * D + D + c] = b[c] - sc * am;
}

// ---------------- layer-3 tail ----------------

__global__ void pool3_kernel(const float* __restrict__ in, const int* __restrict__ goff,
                             const float* __restrict__ param, float* __restrict__ pooled, int SPLIT) {
    int g = blockIdx.x / SPLIT, part = blockIdx.x % SPLIT;
    int start = goff[g], end = goff[g + 1];
    int tid = threadIdx.x;
    int c = tid & 31, sub = tid >> 5;
    float sc = param[(size_t)g * 64 + c], sh = param[(size_t)g * 64 + 32 + c];
    float s = 0.f;
    for (int n = start + part * 8 + sub; n < end; n += SPLIT * 8)
        s += fmaxf(fmaf(sc, in[(size_t)n * 32 + c], sh), 0.f);
    __shared__ float l[256];
    l[tid] = s;
    __syncthreads();
    if (tid < 32) {
        for (int q = 1; q < 8; ++q) s += l[q * 32 + tid];
        atomicAdd(&pooled[(size_t)g * 32 + tid], s);
    }
}

__global__ void lin_kernel(const float* __restrict__ pooled, const int* __restrict__ goff,
                           const float* __restrict__ Wlin, const float* __restrict__ blin,
                           float* __restrict__ out, int nG) {
    int idx = blockIdx.x * blockDim.x + threadIdx.x;
    if (idx >= nG * 2) return;
    int g = idx >> 1, o = idx & 1;
    int cn = goff[g + 1] - goff[g];
    float inv = 1.f / (float)(cn > 1 ? cn : 1);
    float acc = blin[o];
    for (int c = 0; c < 32; ++c) acc = fmaf(pooled[(size_t)g * 32 + c] * inv, Wlin[c * 2 + o], acc);
    out[idx] = acc;
}

// ---------------- launch ----------------

extern "C" void kernel_launch(void* const* d_in, const int* in_sizes, int n_in,
                              void* d_out, int out_size, void* d_ws, size_t ws_size,
                              hipStream_t stream) {
    const float* x    = (const float*)d_in[0];
    const int*  eidx  = (const int*)d_in[1];
    const int*  batch = (const int*)d_in[2];
    const float* Wl1 = (const float*)d_in[3];
    const float* Wr1 = (const float*)d_in[4];
    const float* att1 = (const float*)d_in[5];
    const float* b1 = (const float*)d_in[6];
    const float* g1w = (const float*)d_in[7];
    const float* g1b = (const float*)d_in[8];
    const float* g1a = (const float*)d_in[9];
    const float* Wl2 = (const float*)d_in[10];
    const float* Wr2 = (const float*)d_in[11];
    const float* att2 = (const float*)d_in[12];
    const float* b2 = (const float*)d_in[13];
    const float* g2w = (const float*)d_in[14];
    const float* g2b = (const float*)d_in[15];
    const float* g2a = (const float*)d_in[16];
    const float* Wl3 = (const float*)d_in[17];
    const float* Wr3 = (const float*)d_in[18];
    const float* att3 = (const float*)d_in[19];
    const float* b3 = (const float*)d_in[20];
    const float* g3w = (const float*)d_in[21];
    const float* g3b = (const float*)d_in[22];
    const float* g3a = (const float*)d_in[23];
    const float* Wlin = (const float*)d_in[24];
    const float* blin = (const float*)d_in[25];
    float* outp = (float*)d_out;

    const int N = in_sizes[0] / 64;
    const int E = in_sizes[1] / 2;
    const int Etot = N + E;
    const int G = out_size / 2;
    const int NB = (N + 255) / 256;
    const int P = (N + (1 << PSH) - 1) >> PSH;     // 512-node partitions (<=256)
    const int SPLIT = 16;

    unsigned short* xlb = (unsigned short*)d_ws;           // N*128 bf16
    unsigned short* xrb = xlb + (size_t)N * 128;           // N*128 bf16
    float* agg   = (float*)(xrb + (size_t)N * 128);        // N*64 f32
    float* stats = agg + (size_t)N * 64;
    float* stats1 = stats;
    float* stats2 = stats1 + (size_t)G * 128;
    float* stats3 = stats2 + (size_t)G * 128;
    float* pooled = stats3 + (size_t)G * 64;
    float* param  = pooled + (size_t)G * 32;               // G*128, reused per layer
    int* deg      = (int*)(param + (size_t)G * 128);
    int* rowstart = deg + N;
    int* csr      = rowstart + (N + 1);
    uint* ebuf    = (uint*)(csr + Etot + 16);              // partitioned edge records
    int* bsum     = (int*)(ebuf + Etot);
    int* bofs     = bsum + NB;
    int* goff     = bofs + NB;
    int* gcur     = goff + (G + 1);                        // P+1 partition cursors

    const int* src_idx = eidx;
    const int* dst_idx = eidx + E;

    zero_int_kernel<<<(N + 255) / 256, 256, 0, stream>>>(deg, N);
    zero_int_kernel<<<(G * 352 + 255) / 256, 256, 0, stream>>>((int*)stats, G * 352);

    hist_kernel<<<(Etot + 255) / 256, 256, 0, stream>>>(dst_idx, deg, E, Etot);
    scan1_kernel<<<NB, 256, 0, stream>>>(deg, bsum, N);
    scan2_kernel<<<1, 512, 0, stream>>>(bsum, bofs, NB, rowstart, N, csr + Etot);
    scan3_kernel<<<NB, 256, 0, stream>>>(deg, bofs, rowstart, N);
    init_gcur_kernel<<<(P + 256) / 256, 256, 0, stream>>>(rowstart, gcur, P, N);
    partA_kernel<<<(Etot + 2047) / 2048, 256, 0, stream>>>(src_idx, dst_idx, gcur, ebuf, E, Etot);
    partB_kernel<<<P, 256, 0, stream>>>(ebuf, rowstart, csr, N);
    goff_kernel<<<1, 128, 0, stream>>>(batch, goff, N, G);

    dim3 blk(256);
    int aggGrid = (N + 3) / 4;

    // Layer 1 (fused-W global-x GEMM, 64 nodes/block)
    gemm2_gxf_kernel<false><<<(N + 63) / 64, blk, 0, stream>>>(x, Wl1, Wr1, xlb, xrb, N, nullptr, nullptr);
    agg64_kernel<<<aggGrid, blk, 0, stream>>>(xlb, xrb, rowstart, csr, att1, b1, agg, N);
    gnorm_stats_kernel<64><<<G * SPLIT, blk, 0, stream>>>(agg, goff, stats1, SPLIT);
    gnorm_finalize_kernel<64><<<G, 64, 0, stream>>>(stats1, goff, g1w, g1b, g1a, param);

    // Layer 2 (norm fused into fused-W global-x GEMM)
    gemm2_gxf_kernel<true><<<(N + 63) / 64, blk, 0, stream>>>(agg, Wl2, Wr2, xlb, xrb, N, param, batch);
    agg64_kernel<<<aggGrid, blk, 0, stream>>>(xlb, xrb, rowstart, csr, att2, b2, agg, N);
    gnorm_stats_kernel<64><<<G * SPLIT, blk, 0, stream>>>(agg, goff, stats2, SPLIT);
    gnorm_finalize_kernel<64><<<G, 64, 0, stream>>>(stats2, goff, g2w, g2b, g2a, param);

    // Layer 3 (norm fused into RN=4 transposed-bf16-x GEMM, 128 nodes/block)
    gemm2_sx4_kernel<true><<<(N + 127) / 128, blk, 0, stream>>>(agg, Wl3, Wr3, xlb, xrb, N, param, batch);
    agg128_mean_kernel<<<aggGrid, blk, 0, stream>>>(xlb, xrb, rowstart, csr, att3, b3, agg, N);
    gnorm_stats_kernel<32><<<G * SPLIT, blk, 0, stream>>>(agg, goff, stats3, SPLIT);
    gnorm_finalize_kernel<32><<<G, 32, 0, stream>>>(stats3, goff, g3w, g3b, g3a, param);
    pool3_kernel<<<G * SPLIT, blk, 0, stream>>>(agg, goff, param, pooled, SPLIT);
    lin_kernel<<<(G * 2 + 63) / 64, 64, 0, stream>>>(pooled, goff, Wlin, blin, outp, G);
}

// Round 15
// 462.079 us; speedup vs baseline: 1.1950x; 1.1950x over previous
//
#include <hip/hip_runtime.h>
#include <hip/hip_bf16.h>

#define LEAKY 0.2f
#define EPS_GN 1e-5f
#define PSH 9                    // 512 nodes per partition (P<=256, N<=131072)

typedef unsigned int uint;
typedef __attribute__((ext_vector_type(8))) short bf16x8;
typedef __attribute__((ext_vector_type(4))) float f32x4;

// ---------------- bf16 helpers (storage only; compute fp32) ----------------

__device__ inline float4 bf4(uint lo, uint hi) {
    union { uint u; float f; } a, b, c, d;
    a.u = lo << 16; b.u = lo & 0xFFFF0000u;
    c.u = hi << 16; d.u = hi & 0xFFFF0000u;
    return make_float4(a.f, b.f, c.f, d.f);
}

__device__ inline uint pack_bf2(float lo, float hi) {
    union { float f; uint u; } x, y; x.f = lo; y.f = hi;
    uint ra = x.u + 0x7FFFu + ((x.u >> 16) & 1u);
    uint rb = y.u + 0x7FFFu + ((y.u >> 16) & 1u);
    return (ra >> 16) | (rb & 0xFFFF0000u);
}

__device__ inline unsigned short pack_bf1(float v) {
    union { float f; uint u; } q; q.f = v;
    return (unsigned short)((q.u + 0x7FFFu + ((q.u >> 16) & 1u)) >> 16);
}

// ---------------- CSR build ----------------

__global__ void zero_int_kernel(int* __restrict__ p, int n) {
    int i = blockIdx.x * blockDim.x + threadIdx.x;
    if (i < n) p[i] = 0;
}

__global__ void hist_kernel(const int* __restrict__ dst, int* __restrict__ deg, int E_, int Etot_) {
    int i = blockIdx.x * blockDim.x + threadIdx.x;
    if (i >= Etot_) return;
    int d = (i < E_) ? dst[i] : (i - E_);
    atomicAdd(&deg[d], 1);
}

__global__ void scan1_kernel(const int* __restrict__ deg, int* __restrict__ bsum, int nN) {
    __shared__ int sd[256];
    int i = blockIdx.x * 256 + threadIdx.x;
    sd[threadIdx.x] = (i < nN) ? deg[i] : 0;
    __syncthreads();
    for (int off = 128; off > 0; off >>= 1) {
        if (threadIdx.x < off) sd[threadIdx.x] += sd[threadIdx.x + off];
        __syncthreads();
    }
    if (threadIdx.x == 0) bsum[blockIdx.x] = sd[0];
}

__global__ void scan2_kernel(const int* __restrict__ bsum, int* __restrict__ bofs, int nb,
                             int* __restrict__ rowstart, int nN, int* __restrict__ csr_pad) {
    __shared__ int sd[512];
    int tid = threadIdx.x;
    int v = (tid < nb) ? bsum[tid] : 0;
    sd[tid] = v;
    __syncthreads();
    for (int off = 1; off < 512; off <<= 1) {
        int t = (tid >= off) ? sd[tid - off] : 0;
        __syncthreads();
        sd[tid] += t;
        __syncthreads();
    }
    if (tid < nb) bofs[tid] = sd[tid] - v;
    if (tid == 511) rowstart[nN] = sd[511];
    if (tid < 16) csr_pad[tid] = 0;
}

__global__ void scan3_kernel(const int* __restrict__ deg, const int* __restrict__ bofs,
                             int* __restrict__ rowstart, int nN) {
    __shared__ int sd[256];
    int i = blockIdx.x * 256 + threadIdx.x;
    int v = (i < nN) ? deg[i] : 0;
    sd[threadIdx.x] = v;
    __syncthreads();
    for (int off = 1; off < 256; off <<= 1) {
        int t = (threadIdx.x >= off) ? sd[threadIdx.x - off] : 0;
        __syncthreads();
        sd[threadIdx.x] += t;
        __syncthreads();
    }
    if (i < nN) rowstart[i] = bofs[blockIdx.x] + sd[threadIdx.x] - v;
}

__global__ void init_gcur_kernel(const int* __restrict__ rowstart, int* __restrict__ gcur,
                                 int P, int nN) {
    int p = blockIdx.x * blockDim.x + threadIdx.x;
    if (p > P) return;
    int node = p << PSH;
    if (node > nN) node = nN;
    gcur[p] = rowstart[node];
}

__global__ void partA_kernel(const int* __restrict__ srcs, const int* __restrict__ dsts,
                             int* __restrict__ gcur, uint* __restrict__ ebuf,
                             int E_, int Etot_) {
    __shared__ int hist[256], base_s[256], lcur[256];
    int tid = threadIdx.x;
    hist[tid] = 0; lcur[tid] = 0;
    __syncthreads();
    int i0 = blockIdx.x * 2048 + tid;
    uint rec[8]; int pp[8];
#pragma unroll
    for (int k = 0; k < 8; ++k) {
        int i = i0 + k * 256;
        pp[k] = -1;
        if (i < Etot_) {
            int s, d;
            if (i < E_) { s = srcs[i]; d = dsts[i]; } else { s = i - E_; d = s; }
            int p = d >> PSH;
            pp[k] = p;
            rec[k] = (uint)s | ((uint)(d & ((1 << PSH) - 1)) << 17);
            atomicAdd(&hist[p], 1);
        }
    }
    __syncthreads();
    int h = hist[tid];
    if (h > 0) base_s[tid] = atomicAdd(&gcur[tid], h);
    __syncthreads();
#pragma unroll
    for (int k = 0; k < 8; ++k) {
        if (pp[k] >= 0) {
            int pos = base_s[pp[k]] + atomicAdd(&lcur[pp[k]], 1);
            ebuf[pos] = rec[k];
        }
    }
}

__global__ void partB_kernel(const uint* __restrict__ ebuf, const int* __restrict__ rowstart,
                             int* __restrict__ csr, int nN) {
    __shared__ int lcur[512];
    int tid = threadIdx.x;
    lcur[tid] = 0; lcur[tid + 256] = 0;
    __syncthreads();
    int n0 = blockIdx.x << PSH;
    int n1 = n0 + (1 << PSH);
    if (n1 > nN) n1 = nN;
    int lo = rowstart[n0], hi = rowstart[n1];
    const int* rs = rowstart + n0;
    for (int i = lo + tid; i < hi; i += 256) {
        uint v = ebuf[i];
        int dl = (int)(v >> 17);
        int pos = rs[dl] + atomicAdd(&lcur[dl], 1);
        csr[pos] = (int)(v & 0x1FFFFu);
    }
}

__global__ void goff_kernel(const int* __restrict__ batch, int* __restrict__ goff, int nN, int nG) {
    int g = blockIdx.x * blockDim.x + threadIdx.x;
    if (g > nG) return;
    if (g == nG) { goff[g] = nN; return; }
    int lo = 0, hi = nN;
    while (lo < hi) { int mid = (lo + hi) >> 1; if (batch[mid] < g) lo = mid + 1; else hi = mid; }
    goff[g] = lo;
}

// ---------------- weight prep: transposed bf16 fused [Wl|Wr] -> Wt[col][k] ----------------

__global__ void wtprep_kernel(const float* __restrict__ Wl1, const float* __restrict__ Wr1,
                              const float* __restrict__ Wl2, const float* __restrict__ Wr2,
                              const float* __restrict__ Wl3, const float* __restrict__ Wr3,
                              unsigned short* __restrict__ wt1, unsigned short* __restrict__ wt2,
                              unsigned short* __restrict__ wt3) {
    int idx = blockIdx.x * 256 + threadIdx.x;
    if (idx < 8192) {
        int col = idx >> 6, k = idx & 63;
        float v = (col < 64) ? Wl1[k * 64 + col] : Wr1[k * 64 + (col - 64)];
        wt1[col * 64 + k] = pack_bf1(v);
    } else if (idx < 16384) {
        int i = idx - 8192; int col = i >> 6, k = i & 63;
        float v = (col < 64) ? Wl2[k * 64 + col] : Wr2[k * 64 + (col - 64)];
        wt2[col * 64 + k] = pack_bf1(v);
    } else if (idx < 32768) {
        int i = idx - 16384; int col = i >> 6, k = i & 63;
        float v = (col < 128) ? Wl3[k * 128 + col] : Wr3[k * 128 + (col - 128)];
        wt3[col * 64 + k] = pack_bf1(v);
    }
}

// ---------------- MFMA GEMM: [xl|xr] = f(x) @ [Wl|Wr], bf16 in/out, fp32 accum ----------------
// 64 nodes/block, 4 waves x 16 nodes. Swapped operands: mfma(W_frag, X_frag, acc) so each
// lane's 4 acc regs are 4 consecutive output cols of one node -> packed 8B stores.
// LDS: Xs[node][k] bf16 + Ws[col][k] bf16, both XOR-swizzled (byte ^= (row&7)<<4, 16B chunks).

template <int NCOLS, bool NORM>
__global__ __launch_bounds__(256, 4)
void gemm_mfma_kernel(const float* __restrict__ x, const unsigned short* __restrict__ Wt,
                      unsigned short* __restrict__ xl, unsigned short* __restrict__ xr,
                      int nN, const float* __restrict__ param, const int* __restrict__ batch) {
    constexpr int NT = NCOLS / 16;
    constexpr int OD = NCOLS / 2;           // per-output stride (64 / 128)
    __shared__ unsigned short Xs[64 * 64];
    __shared__ unsigned short Ws[NCOLS * 64];
    int tid = threadIdx.x;
    int node0 = blockIdx.x * 64;

    // stage X (bf16, norm applied, swizzled): thread = (node, 16-k chunk)
    {
        int nl = tid >> 2, k0 = (tid & 3) * 16;
        int n = node0 + nl;
        bool v = n < nN;
        int nc = v ? n : 0;
        const float* xrow = x + (size_t)nc * 64 + k0;
        const float* scp = nullptr; const float* shp = nullptr;
        if constexpr (NORM) {
            int g = batch[nc];
            scp = param + (size_t)g * 128 + k0;
            shp = param + (size_t)g * 128 + 64 + k0;
        }
        uint q[8];
#pragma unroll
        for (int j = 0; j < 8; ++j) {
            float a = v ? xrow[j * 2] : 0.f;
            float b = v ? xrow[j * 2 + 1] : 0.f;
            if constexpr (NORM) {
                a = fmaxf(fmaf(scp[j * 2], a, shp[j * 2]), 0.f);
                b = fmaxf(fmaf(scp[j * 2 + 1], b, shp[j * 2 + 1]), 0.f);
            }
            q[j] = pack_bf2(a, b);
        }
        char* base = (char*)Xs + nl * 128;
        uint sw = (uint)(nl & 7) << 4;
        *(uint4*)(base + (((uint)(k0 * 2)) ^ sw))      = make_uint4(q[0], q[1], q[2], q[3]);
        *(uint4*)(base + (((uint)(k0 * 2 + 16)) ^ sw)) = make_uint4(q[4], q[5], q[6], q[7]);
    }
    // stage Wt (bf16 [col][64], 16B chunks, swizzled)
    for (int ch = tid; ch < NCOLS * 8; ch += 256) {
        int col = ch >> 3, sub = ch & 7;
        uint4 q = ((const uint4*)(Wt + col * 64))[sub];
        *(uint4*)((char*)Ws + col * 128 + (((uint)(sub * 16)) ^ ((uint)(col & 7) << 4))) = q;
    }
    __syncthreads();

    int lane = tid & 63;
    int wv = tid >> 6;
    int l15 = lane & 15, quad = lane >> 4;

    // X fragments (B operand): this wave's 16 nodes; lane: node=l15, k=quad*8+j (+32 for h=1)
    bf16x8 xf[2];
    {
        int row = wv * 16 + l15;
        char* base = (char*)Xs + row * 128;
        uint sw = (uint)(row & 7) << 4;
        xf[0] = *(bf16x8*)(base + (((uint)(quad * 16)) ^ sw));
        xf[1] = *(bf16x8*)(base + (((uint)(64 + quad * 16)) ^ sw));
    }
    f32x4 acc[NT];
#pragma unroll
    for (int t = 0; t < NT; ++t) acc[t] = (f32x4){0.f, 0.f, 0.f, 0.f};
#pragma unroll
    for (int t = 0; t < NT; ++t) {
        int col = t * 16 + l15;
        char* base = (char*)Ws + col * 128;
        uint sw = (uint)(col & 7) << 4;
        bf16x8 a0 = *(bf16x8*)(base + (((uint)(quad * 16)) ^ sw));
        bf16x8 a1 = *(bf16x8*)(base + (((uint)(64 + quad * 16)) ^ sw));
        acc[t] = __builtin_amdgcn_mfma_f32_16x16x32_bf16(a0, xf[0], acc[t], 0, 0, 0);
        acc[t] = __builtin_amdgcn_mfma_f32_16x16x32_bf16(a1, xf[1], acc[t], 0, 0, 0);
    }
    // epilogue: lane owns node=l15 of its wave; acc[t][r] = col (t*16 + quad*4 + r)
    int node = node0 + wv * 16 + l15;
    if (node < nN) {
#pragma unroll
        for (int t = 0; t < NT; ++t) {
            int cg = t * 16 + quad * 4;
            unsigned short* outp = (cg < OD) ? xl : xr;
            int ocol = (cg < OD) ? cg : cg - OD;
            uint2 pk;
            pk.x = pack_bf2(acc[t][0], acc[t][1]);
            pk.y = pack_bf2(acc[t][2], acc[t][3]);
            *(uint2*)(outp + (size_t)node * OD + ocol) = pk;
        }
    }
}

// ---------------- Aggregate layer 1-2: D=64, H=4, C=16, concat ----------------

__global__ void agg64_kernel(const unsigned short* __restrict__ xl, const unsigned short* __restrict__ xr,
                             const int* __restrict__ rowstart, const int* __restrict__ csr,
                             const float* __restrict__ att, const float* __restrict__ bias,
                             float* __restrict__ out, int nN) {
    int wid = (blockIdx.x * blockDim.x + threadIdx.x) >> 6;
    int lane = threadIdx.x & 63;
    if (wid >= nN) return;
    int c8 = lane & 7;
    int sg = lane >> 3;
    const uint4* xl4 = (const uint4*)xl;
    const float LOG2E = 1.4426950408889634f;
    float4 attA = ((const float4*)att)[c8 * 2];
    float4 attB = ((const float4*)att)[c8 * 2 + 1];
    attA.x *= LOG2E; attA.y *= LOG2E; attA.z *= LOG2E; attA.w *= LOG2E;
    attB.x *= LOG2E; attB.y *= LOG2E; attB.z *= LOG2E; attB.w *= LOG2E;
    uint4 xru = ((const uint4*)xr)[(size_t)wid * 8 + c8];
    float4 xrA = bf4(xru.x, xru.y), xrB = bf4(xru.z, xru.w);
    int rs = rowstart[wid], re = rowstart[wid + 1];
    int nIt = (re - rs + 7) >> 3;
    float den = 0.f;
    float4 accA = make_float4(0.f, 0.f, 0.f, 0.f);
    float4 accB = make_float4(0.f, 0.f, 0.f, 0.f);
    int i = rs + sg;
    int s = csr[i];
    uint4 xv = xl4[(size_t)s * 8 + c8];
    for (int it = 0; it < nIt; ++it) {
        float4 curA = bf4(xv.x, xv.y), curB = bf4(xv.z, xv.w);
        bool vv = i < re;
        i += 8;
        s = csr[i];
        xv = xl4[(size_t)s * 8 + c8];
        float4 mA, mB;
        mA.x = curA.x + xrA.x; mA.y = curA.y + xrA.y;
        mA.z = curA.z + xrA.z; mA.w = curA.w + xrA.w;
        mB.x = curB.x + xrB.x; mB.y = curB.y + xrB.y;
        mB.z = curB.z + xrB.z; mB.w = curB.w + xrB.w;
        mA.x = fmaxf(mA.x, LEAKY * mA.x); mA.y = fmaxf(mA.y, LEAKY * mA.y);
        mA.z = fmaxf(mA.z, LEAKY * mA.z); mA.w = fmaxf(mA.w, LEAKY * mA.w);
        mB.x = fmaxf(mB.x, LEAKY * mB.x); mB.y = fmaxf(mB.y, LEAKY * mB.y);
        mB.z = fmaxf(mB.z, LEAKY * mB.z); mB.w = fmaxf(mB.w, LEAKY * mB.w);
        float p = mA.x * attA.x;
        p = fmaf(mA.y, attA.y, p); p = fmaf(mA.z, attA.z, p); p = fmaf(mA.w, attA.w, p);
        p = fmaf(mB.x, attB.x, p); p = fmaf(mB.y, attB.y, p);
        p = fmaf(mB.z, attB.z, p); p = fmaf(mB.w, attB.w, p);
        p += __shfl_xor(p, 1);
        float w = vv ? exp2f(p) : 0.f;
        den += w;
        accA.x = fmaf(w, curA.x, accA.x); accA.y = fmaf(w, curA.y, accA.y);
        accA.z = fmaf(w, curA.z, accA.z); accA.w = fmaf(w, curA.w, accA.w);
        accB.x = fmaf(w, curB.x, accB.x); accB.y = fmaf(w, curB.y, accB.y);
        accB.z = fmaf(w, curB.z, accB.z); accB.w = fmaf(w, curB.w, accB.w);
    }
#pragma unroll
    for (int off = 8; off <= 32; off <<= 1) {
        den    += __shfl_xor(den, off);
        accA.x += __shfl_xor(accA.x, off); accA.y += __shfl_xor(accA.y, off);
        accA.z += __shfl_xor(accA.z, off); accA.w += __shfl_xor(accA.w, off);
        accB.x += __shfl_xor(accB.x, off); accB.y += __shfl_xor(accB.y, off);
        accB.z += __shfl_xor(accB.z, off); accB.w += __shfl_xor(accB.w, off);
    }
    if (lane < 8) {
        float4 bvA = ((const float4*)bias)[c8 * 2];
        float4 bvB = ((const float4*)bias)[c8 * 2 + 1];
        float inv = 1.f / den;
        float4 rA, rB;
        rA.x = fmaf(accA.x, inv, bvA.x); rA.y = fmaf(accA.y, inv, bvA.y);
        rA.z = fmaf(accA.z, inv, bvA.z); rA.w = fmaf(accA.w, inv, bvA.w);
        rB.x = fmaf(accB.x, inv, bvB.x); rB.y = fmaf(accB.y, inv, bvB.y);
        rB.z = fmaf(accB.z, inv, bvB.z); rB.w = fmaf(accB.w, inv, bvB.w);
        ((float4*)out)[(size_t)wid * 16 + c8 * 2]     = rA;
        ((float4*)out)[(size_t)wid * 16 + c8 * 2 + 1] = rB;
    }
}

// ---------------- Aggregate layer 3: D=128, H=4, C=32, head-mean ----------------

__global__ void agg128_mean_kernel(const unsigned short* __restrict__ xl, const unsigned short* __restrict__ xr,
                                   const int* __restrict__ rowstart, const int* __restrict__ csr,
                                   const float* __restrict__ att, const float* __restrict__ bias,
                                   float* __restrict__ out, int nN) {
    int wid = (blockIdx.x * blockDim.x + threadIdx.x) >> 6;
    int lane = threadIdx.x & 63;
    if (wid >= nN) return;
    int c8 = lane & 15;
    int sg = lane >> 4;
    const uint4* xl4 = (const uint4*)xl;
    const float LOG2E = 1.4426950408889634f;
    float4 attA = ((const float4*)att)[c8 * 2];
    float4 attB = ((const float4*)att)[c8 * 2 + 1];
    attA.x *= LOG2E; attA.y *= LOG2E; attA.z *= LOG2E; attA.w *= LOG2E;
    attB.x *= LOG2E; attB.y *= LOG2E; attB.z *= LOG2E; attB.w *= LOG2E;
    uint4 xru = ((const uint4*)xr)[(size_t)wid * 16 + c8];
    float4 xrA = bf4(xru.x, xru.y), xrB = bf4(xru.z, xru.w);
    int rs = rowstart[wid], re = rowstart[wid + 1];
    int nIt = (re - rs + 3) >> 2;
    float den = 0.f;
    float4 accA = make_float4(0.f, 0.f, 0.f, 0.f);
    float4 accB = make_float4(0.f, 0.f, 0.f, 0.f);
    int i = rs + sg;
    int s = csr[i];
    uint4 xv = xl4[(size_t)s * 16 + c8];
    for (int it = 0; it < nIt; ++it) {
        float4 curA = bf4(xv.x, xv.y), curB = bf4(xv.z, xv.w);
        bool vv = i < re;
        i += 4;
        s = csr[i];
        xv = xl4[(size_t)s * 16 + c8];
        float4 mA, mB;
        mA.x = curA.x + xrA.x; mA.y = curA.y + xrA.y;
        mA.z = curA.z + xrA.z; mA.w = curA.w + xrA.w;
        mB.x = curB.x + xrB.x; mB.y = curB.y + xrB.y;
        mB.z = curB.z + xrB.z; mB.w = curB.w + xrB.w;
        mA.x = fmaxf(mA.x, LEAKY * mA.x); mA.y = fmaxf(mA.y, LEAKY * mA.y);
        mA.z = fmaxf(mA.z, LEAKY * mA.z); mA.w = fmaxf(mA.w, LEAKY * mA.w);
        mB.x = fmaxf(mB.x, LEAKY * mB.x); mB.y = fmaxf(mB.y, LEAKY * mB.y);
        mB.z = fmaxf(mB.z, LEAKY * mB.z); mB.w = fmaxf(mB.w, LEAKY * mB.w);
        float p = mA.x * attA.x;
        p = fmaf(mA.y, attA.y, p); p = fmaf(mA.z, attA.z, p); p = fmaf(mA.w, attA.w, p);
        p = fmaf(mB.x, attB.x, p); p = fmaf(mB.y, attB.y, p);
        p = fmaf(mB.z, attB.z, p); p = fmaf(mB.w, attB.w, p);
        p += __shfl_xor(p, 1);
        p += __shfl_xor(p, 2);
        float w = vv ? exp2f(p) : 0.f;
        den += w;
        accA.x = fmaf(w, curA.x, accA.x); accA.y = fmaf(w, curA.y, accA.y);
        accA.z = fmaf(w, curA.z, accA.z); accA.w = fmaf(w, curA.w, accA.w);
        accB.x = fmaf(w, curB.x, accB.x); accB.y = fmaf(w, curB.y, accB.y);
        accB.z = fmaf(w, curB.z, accB.z); accB.w = fmaf(w, curB.w, accB.w);
    }
#pragma unroll
    for (int off = 16; off <= 32; off <<= 1) {
        den    += __shfl_xor(den, off);
        accA.x += __shfl_xor(accA.x, off); accA.y += __shfl_xor(accA.y, off);
        accA.z += __shfl_xor(accA.z, off); accA.w += __shfl_xor(accA.w, off);
        accB.x += __shfl_xor(accB.x, off); accB.y += __shfl_xor(accB.y, off);
        accB.z += __shfl_xor(accB.z, off); accB.w += __shfl_xor(accB.w, off);
    }
    float inv = 1.f / den;
    float4 rA, rB;
    rA.x = accA.x * inv; rA.y = accA.y * inv; rA.z = accA.z * inv; rA.w = accA.w * inv;
    rB.x = accB.x * inv; rB.y = accB.y * inv; rB.z = accB.z * inv; rB.w = accB.w * inv;
#pragma unroll
    for (int off = 4; off <= 8; off <<= 1) {
        rA.x += __shfl_xor(rA.x, off); rA.y += __shfl_xor(rA.y, off);
        rA.z += __shfl_xor(rA.z, off); rA.w += __shfl_xor(rA.w, off);
        rB.x += __shfl_xor(rB.x, off); rB.y += __shfl_xor(rB.y, off);
        rB.z += __shfl_xor(rB.z, off); rB.w += __shfl_xor(rB.w, off);
    }
    if (lane < 4) {
        float4 bvA = ((const float4*)bias)[lane * 2];
        float4 bvB = ((const float4*)bias)[lane * 2 + 1];
        float4 oA, oB;
        oA.x = fmaf(rA.x, 0.25f, bvA.x); oA.y = fmaf(rA.y, 0.25f, bvA.y);
        oA.z = fmaf(rA.z, 0.25f, bvA.z); oA.w = fmaf(rA.w, 0.25f, bvA.w);
        oB.x = fmaf(rB.x, 0.25f, bvB.x); oB.y = fmaf(rB.y, 0.25f, bvB.y);
        oB.z = fmaf(rB.z, 0.25f, bvB.z); oB.w = fmaf(rB.w, 0.25f, bvB.w);
        ((float4*)out)[(size_t)wid * 8 + lane * 2]     = oA;
        ((float4*)out)[(size_t)wid * 8 + lane * 2 + 1] = oB;
    }
}

// ---------------- GraphNorm stats / finalize ----------------

template <int D>
__global__ void gnorm_stats_kernel(const float* __restrict__ in, const int* __restrict__ goff,
                                   float* __restrict__ stats, int SPLIT) {
    int g = blockIdx.x / SPLIT, part = blockIdx.x % SPLIT;
    int start = goff[g], end = goff[g + 1];
    constexpr int RPB = 256 / D;
    int tid = threadIdx.x;
    int c = tid % D, sub = tid / D;
    float s1 = 0.f, s2 = 0.f;
    for (int n = start + part * RPB + sub; n < end; n += SPLIT * RPB) {
        float v = in[(size_t)n * D + c];
        s1 += v; s2 += v * v;
    }
    __shared__ float l1[256], l2[256];
    l1[tid] = s1; l2[tid] = s2;
    __syncthreads();
    if (tid < D) {
        for (int s = 1; s < RPB; ++s) { s1 += l1[s * D + tid]; s2 += l2[s * D + tid]; }
        atomicAdd(&stats[(size_t)g * 2 * D + tid], s1);
        atomicAdd(&stats[(size_t)g * 2 * D + D + tid], s2);
    }
}

template <int D>
__global__ void gnorm_finalize_kernel(const float* __restrict__ stats, const int* __restrict__ goff,
                                      const float* __restrict__ w, const float* __restrict__ b,
                                      const float* __restrict__ a, float* __restrict__ param) {
    int g = blockIdx.x, c = threadIdx.x;
    if (c >= D) return;
    int cn = goff[g + 1] - goff[g];
    float cnt = (float)(cn > 1 ? cn : 1);
    float S1 = stats[(size_t)g * 2 * D + c], S2 = stats[(size_t)g * 2 * D + D + c];
    float mu = S1 / cnt;
    float am = a[c] * mu;
    float var = S2 / cnt - 2.f * am * mu + am * am;
    float sc = w[c] * rsqrtf(var + EPS_GN);
    param[(size_t)g * 2 * D + c] = sc;
    param[(size_t)g * 2 * D + D + c] = b[c] - sc * am;
}

// ---------------- layer-3 tail ----------------

__global__ void pool3_kernel(const float* __restrict__ in, const int* __restrict__ goff,
                             const float* __restrict__ param, float* __restrict__ pooled, int SPLIT) {
    int g = blockIdx.x / SPLIT, part = blockIdx.x % SPLIT;
    int start = goff[g], end = goff[g + 1];
    int tid = threadIdx.x;
    int c = tid & 31, sub = tid >> 5;
    float sc = param[(size_t)g * 64 + c], sh = param[(size_t)g * 64 + 32 + c];
    float s = 0.f;
    for (int n = start + part * 8 + sub; n < end; n += SPLIT * 8)
        s += fmaxf(fmaf(sc, in[(size_t)n * 32 + c], sh), 0.f);
    __shared__ float l[256];
    l[tid] = s;
    __syncthreads();
    if (tid < 32) {
        for (int q = 1; q < 8; ++q) s += l[q * 32 + tid];
        atomicAdd(&pooled[(size_t)g * 32 + tid], s);
    }
}

__global__ void lin_kernel(const float* __restrict__ pooled, const int* __restrict__ goff,
                           const float* __restrict__ Wlin, const float* __restrict__ blin,
                           float* __restrict__ out, int nG) {
    int idx = blockIdx.x * blockDim.x + threadIdx.x;
    if (idx >= nG * 2) return;
    int g = idx >> 1, o = idx & 1;
    int cn = goff[g + 1] - goff[g];
    float inv = 1.f / (float)(cn > 1 ? cn : 1);
    float acc = blin[o];
    for (int c = 0; c < 32; ++c) acc = fmaf(pooled[(size_t)g * 32 + c] * inv, Wlin[c * 2 + o], acc);
    out[idx] = acc;
}

// ---------------- launch ----------------

extern "C" void kernel_launch(void* const* d_in, const int* in_sizes, int n_in,
                              void* d_out, int out_size, void* d_ws, size_t ws_size,
                              hipStream_t stream) {
    const float* x    = (const float*)d_in[0];
    const int*  eidx  = (const int*)d_in[1];
    const int*  batch = (const int*)d_in[2];
    const float* Wl1 = (const float*)d_in[3];
    const float* Wr1 = (const float*)d_in[4];
    const float* att1 = (const float*)d_in[5];
    const float* b1 = (const float*)d_in[6];
    const float* g1w = (const float*)d_in[7];
    const float* g1b = (const float*)d_in[8];
    const float* g1a = (const float*)d_in[9];
    const float* Wl2 = (const float*)d_in[10];
    const float* Wr2 = (const float*)d_in[11];
    const float* att2 = (const float*)d_in[12];
    const float* b2 = (const float*)d_in[13];
    const float* g2w = (const float*)d_in[14];
    const float* g2b = (const float*)d_in[15];
    const float* g2a = (const float*)d_in[16];
    const float* Wl3 = (const float*)d_in[17];
    const float* Wr3 = (const float*)d_in[18];
    const float* att3 = (const float*)d_in[19];
    const float* b3 = (const float*)d_in[20];
    const float* g3w = (const float*)d_in[21];
    const float* g3b = (const float*)d_in[22];
    const float* g3a = (const float*)d_in[23];
    const float* Wlin = (const float*)d_in[24];
    const float* blin = (const float*)d_in[25];
    float* outp = (float*)d_out;

    const int N = in_sizes[0] / 64;
    const int E = in_sizes[1] / 2;
    const int Etot = N + E;
    const int G = out_size / 2;
    const int NB = (N + 255) / 256;
    const int P = (N + (1 << PSH) - 1) >> PSH;
    const int SPLIT = 16;

    unsigned short* xlb = (unsigned short*)d_ws;           // N*128 bf16
    unsigned short* xrb = xlb + (size_t)N * 128;           // N*128 bf16
    float* agg   = (float*)(xrb + (size_t)N * 128);        // N*64 f32
    float* stats = agg + (size_t)N * 64;
    float* stats1 = stats;
    float* stats2 = stats1 + (size_t)G * 128;
    float* stats3 = stats2 + (size_t)G * 128;
    float* pooled = stats3 + (size_t)G * 64;
    float* param  = pooled + (size_t)G * 32;               // G*128, reused per layer
    int* deg      = (int*)(param + (size_t)G * 128);
    int* rowstart = deg + N;
    int* csr      = rowstart + (N + 1);
    uint* ebuf    = (uint*)(csr + Etot + 16);
    int* bsum     = (int*)(ebuf + Etot);
    int* bofs     = bsum + NB;
    int* goff     = bofs + NB;
    int* gcur     = goff + (G + 1);
    unsigned short* wt1 = (unsigned short*)(gcur + P + 1); // 128*64 bf16
    unsigned short* wt2 = wt1 + 8192;                      // 128*64
    unsigned short* wt3 = wt2 + 8192;                      // 256*64

    const int* src_idx = eidx;
    const int* dst_idx = eidx + E;

    zero_int_kernel<<<(N + 255) / 256, 256, 0, stream>>>(deg, N);
    zero_int_kernel<<<(G * 352 + 255) / 256, 256, 0, stream>>>((int*)stats, G * 352);
    wtprep_kernel<<<128, 256, 0, stream>>>(Wl1, Wr1, Wl2, Wr2, Wl3, Wr3, wt1, wt2, wt3);

    hist_kernel<<<(Etot + 255) / 256, 256, 0, stream>>>(dst_idx, deg, E, Etot);
    scan1_kernel<<<NB, 256, 0, stream>>>(deg, bsum, N);
    scan2_kernel<<<1, 512, 0, stream>>>(bsum, bofs, NB, rowstart, N, csr + Etot);
    scan3_kernel<<<NB, 256, 0, stream>>>(deg, bofs, rowstart, N);
    init_gcur_kernel<<<(P + 256) / 256, 256, 0, stream>>>(rowstart, gcur, P, N);
    partA_kernel<<<(Etot + 2047) / 2048, 256, 0, stream>>>(src_idx, dst_idx, gcur, ebuf, E, Etot);
    partB_kernel<<<P, 256, 0, stream>>>(ebuf, rowstart, csr, N);
    goff_kernel<<<1, 128, 0, stream>>>(batch, goff, N, G);

    dim3 blk(256);
    int aggGrid = (N + 3) / 4;
    int gemmGrid = (N + 63) / 64;

    // Layer 1
    gemm_mfma_kernel<128, false><<<gemmGrid, blk, 0, stream>>>(x, wt1, xlb, xrb, N, nullptr, nullptr);
    agg64_kernel<<<aggGrid, blk, 0, stream>>>(xlb, xrb, rowstart, csr, att1, b1, agg, N);
    gnorm_stats_kernel<64><<<G * SPLIT, blk, 0, stream>>>(agg, goff, stats1, SPLIT);
    gnorm_finalize_kernel<64><<<G, 64, 0, stream>>>(stats1, goff, g1w, g1b, g1a, param);

    // Layer 2 (norm fused into GEMM X-staging)
    gemm_mfma_kernel<128, true><<<gemmGrid, blk, 0, stream>>>(agg, wt2, xlb, xrb, N, param, batch);
    agg64_kernel<<<aggGrid, blk, 0, stream>>>(xlb, xrb, rowstart, csr, att2, b2, agg, N);
    gnorm_stats_kernel<64><<<G * SPLIT, blk, 0, stream>>>(agg, goff, stats2, SPLIT);
    gnorm_finalize_kernel<64><<<G, 64, 0, stream>>>(stats2, goff, g2w, g2b, g2a, param);

    // Layer 3 (norm fused into GEMM X-staging; 256 fused cols)
    gemm_mfma_kernel<256, true><<<gemmGrid, blk, 0, stream>>>(agg, wt3, xlb, xrb, N, param, batch);
    agg128_mean_kernel<<<aggGrid, blk, 0, stream>>>(xlb, xrb, rowstart, csr, att3, b3, agg, N);
    gnorm_stats_kernel<32><<<G * SPLIT, blk, 0, stream>>>(agg, goff, stats3, SPLIT);
    gnorm_finalize_kernel<32><<<G, 32, 0, stream>>>(stats3, goff, g3w, g3b, g3a, param);
    pool3_kernel<<<G * SPLIT, blk, 0, stream>>>(agg, goff, param, pooled, SPLIT);
    lin_kernel<<<(G * 2 + 63) / 64, 64, 0, stream>>>(pooled, goff, Wlin, blin, outp, G);
}

// Round 16
// 408.935 us; speedup vs baseline: 1.3503x; 1.1300x over previous
//
#include <hip/hip_runtime.h>
#include <hip/hip_bf16.h>

#define LEAKY 0.2f
#define EPS_GN 1e-5f
#define PSH 9                    // 512 nodes per partition (P<=256, N<=131072)

typedef unsigned int uint;
typedef __attribute__((ext_vector_type(8))) short bf16x8;
typedef __attribute__((ext_vector_type(4))) float f32x4;

// ---------------- bf16 helpers (storage only; compute fp32) ----------------

__device__ inline float4 bf4(uint lo, uint hi) {
    union { uint u; float f; } a, b, c, d;
    a.u = lo << 16; b.u = lo & 0xFFFF0000u;
    c.u = hi << 16; d.u = hi & 0xFFFF0000u;
    return make_float4(a.f, b.f, c.f, d.f);
}

__device__ inline uint pack_bf2(float lo, float hi) {
    union { float f; uint u; } x, y; x.f = lo; y.f = hi;
    uint ra = x.u + 0x7FFFu + ((x.u >> 16) & 1u);
    uint rb = y.u + 0x7FFFu + ((y.u >> 16) & 1u);
    return (ra >> 16) | (rb & 0xFFFF0000u);
}

__device__ inline unsigned short pack_bf1(float v) {
    union { float f; uint u; } q; q.f = v;
    return (unsigned short)((q.u + 0x7FFFu + ((q.u >> 16) & 1u)) >> 16);
}

// ---------------- fused setup: zero stats, wtprep, pcnt=0, csr pad, goff ----------------

__global__ void setup_kernel(float* __restrict__ stats, int statN,
                             const float* __restrict__ Wl1, const float* __restrict__ Wr1,
                             const float* __restrict__ Wl2, const float* __restrict__ Wr2,
                             const float* __restrict__ Wl3, const float* __restrict__ Wr3,
                             unsigned short* __restrict__ wt1, unsigned short* __restrict__ wt2,
                             unsigned short* __restrict__ wt3,
                             int* __restrict__ pcnt, int* __restrict__ csr_pad,
                             const int* __restrict__ batch, int* __restrict__ goff,
                             int nN, int nG) {
    int idx = blockIdx.x * 256 + threadIdx.x;
    if (idx < statN) { stats[idx] = 0.f; return; }
    idx -= statN;
    if (idx < 8192) {
        int col = idx >> 6, k = idx & 63;
        float v = (col < 64) ? Wl1[k * 64 + col] : Wr1[k * 64 + (col - 64)];
        wt1[col * 64 + k] = pack_bf1(v);
        return;
    }
    idx -= 8192;
    if (idx < 8192) {
        int col = idx >> 6, k = idx & 63;
        float v = (col < 64) ? Wl2[k * 64 + col] : Wr2[k * 64 + (col - 64)];
        wt2[col * 64 + k] = pack_bf1(v);
        return;
    }
    idx -= 8192;
    if (idx < 16384) {
        int col = idx >> 6, k = idx & 63;
        float v = (col < 128) ? Wl3[k * 128 + col] : Wr3[k * 128 + (col - 128)];
        wt3[col * 64 + k] = pack_bf1(v);
        return;
    }
    idx -= 16384;
    if (idx < 256) { pcnt[idx] = 0; return; }
    idx -= 256;
    if (idx < 16) { csr_pad[idx] = 0; return; }
    idx -= 16;
    if (idx <= nG) {
        if (idx == nG) { goff[idx] = nN; return; }
        int lo = 0, hi = nN;
        while (lo < hi) { int mid = (lo + hi) >> 1; if (batch[mid] < idx) lo = mid + 1; else hi = mid; }
        goff[idx] = lo;
    }
}

// ---------------- partition edge counts (block-aggregated) ----------------

__global__ void pcount_kernel(const int* __restrict__ dsts, int* __restrict__ pcnt,
                              int E_, int Etot_) {
    __shared__ int h[256];
    int tid = threadIdx.x;
    h[tid] = 0;
    __syncthreads();
    int i0 = blockIdx.x * 2048 + tid;
#pragma unroll
    for (int k = 0; k < 8; ++k) {
        int i = i0 + k * 256;
        if (i < Etot_) {
            int d = (i < E_) ? dsts[i] : (i - E_);
            atomicAdd(&h[d >> PSH], 1);
        }
    }
    __syncthreads();
    if (h[tid] > 0) atomicAdd(&pcnt[tid], h[tid]);
}

// scan 256 partition counts -> pstart & gcur; also rowstart[N]
__global__ void pscan_kernel(const int* __restrict__ pcnt, int* __restrict__ pstart,
                             int* __restrict__ gcur, int* __restrict__ rowstart, int nN) {
    __shared__ int sd[256];
    int t = threadIdx.x;
    int v = pcnt[t];
    sd[t] = v;
    __syncthreads();
    for (int off = 1; off < 256; off <<= 1) {
        int tmp = (t >= off) ? sd[t - off] : 0;
        __syncthreads();
        sd[t] += tmp;
        __syncthreads();
    }
    int excl = sd[t] - v;
    pstart[t] = excl;
    gcur[t] = excl;
    if (t == 255) {
        pstart[256] = sd[255];
        gcur[256] = sd[255];
        rowstart[nN] = sd[255];
    }
}

// Phase A: block-aggregated partition scatter. rec = src | dst_local<<17.
__global__ void partA_kernel(const int* __restrict__ srcs, const int* __restrict__ dsts,
                             int* __restrict__ gcur, uint* __restrict__ ebuf,
                             int E_, int Etot_) {
    __shared__ int hist[256], base_s[256], lcur[256];
    int tid = threadIdx.x;
    hist[tid] = 0; lcur[tid] = 0;
    __syncthreads();
    int i0 = blockIdx.x * 2048 + tid;
    uint rec[8]; int pp[8];
#pragma unroll
    for (int k = 0; k < 8; ++k) {
        int i = i0 + k * 256;
        pp[k] = -1;
        if (i < Etot_) {
            int s, d;
            if (i < E_) { s = srcs[i]; d = dsts[i]; } else { s = i - E_; d = s; }
            int p = d >> PSH;
            pp[k] = p;
            rec[k] = (uint)s | ((uint)(d & ((1 << PSH) - 1)) << 17);
            atomicAdd(&hist[p], 1);
        }
    }
    __syncthreads();
    int h = hist[tid];
    if (h > 0) base_s[tid] = atomicAdd(&gcur[tid], h);
    __syncthreads();
#pragma unroll
    for (int k = 0; k < 8; ++k) {
        if (pp[k] >= 0) {
            int pos = base_s[pp[k]] + atomicAdd(&lcur[pp[k]], 1);
            ebuf[pos] = rec[k];
        }
    }
}

// Phase B2: per partition, local histogram + scan -> rowstart + dense csr scatter.
__global__ void partB2_kernel(const uint* __restrict__ ebuf, const int* __restrict__ pstart,
                              int* __restrict__ rowstart, int* __restrict__ csr, int nN) {
    __shared__ int cnt[512], ofs[512], ssum[256];
    int t = threadIdx.x;
    cnt[t] = 0; cnt[t + 256] = 0;
    __syncthreads();
    int p = blockIdx.x;
    int lo = pstart[p], hi = pstart[p + 1];
    for (int i = lo + t; i < hi; i += 256)
        atomicAdd(&cnt[ebuf[i] >> 17], 1);
    __syncthreads();
    int a = cnt[2 * t], b = cnt[2 * t + 1];
    ssum[t] = a + b;
    __syncthreads();
    for (int off = 1; off < 256; off <<= 1) {
        int tmp = (t >= off) ? ssum[t - off] : 0;
        __syncthreads();
        ssum[t] += tmp;
        __syncthreads();
    }
    int base = (t > 0) ? ssum[t - 1] : 0;
    ofs[2 * t] = lo + base;
    ofs[2 * t + 1] = lo + base + a;
    __syncthreads();
    int n0 = p << PSH;
#pragma unroll
    for (int j = t; j < 512; j += 256) {
        int n = n0 + j;
        if (n < nN) rowstart[n] = ofs[j];
    }
    __syncthreads();          // rowstart written before ofs used as cursors
    for (int i = lo + t; i < hi; i += 256) {
        uint v = ebuf[i];
        int pos = atomicAdd(&ofs[v >> 17], 1);
        csr[pos] = (int)(v & 0x1FFFFu);
    }
}

// ---------------- MFMA GEMM: [xl|xr] = f(x) @ [Wl|Wr], bf16 in/out, fp32 accum ----------------

template <int NCOLS, bool NORM>
__global__ __launch_bounds__(256, 4)
void gemm_mfma_kernel(const float* __restrict__ x, const unsigned short* __restrict__ Wt,
                      unsigned short* __restrict__ xl, unsigned short* __restrict__ xr,
                      int nN, const float* __restrict__ param, const int* __restrict__ batch) {
    constexpr int NT = NCOLS / 16;
    constexpr int OD = NCOLS / 2;
    __shared__ unsigned short Xs[64 * 64];
    __shared__ unsigned short Ws[NCOLS * 64];
    int tid = threadIdx.x;
    int node0 = blockIdx.x * 64;

    {
        int nl = tid >> 2, k0 = (tid & 3) * 16;
        int n = node0 + nl;
        bool v = n < nN;
        int nc = v ? n : 0;
        const float* xrow = x + (size_t)nc * 64 + k0;
        const float* scp = nullptr; const float* shp = nullptr;
        if constexpr (NORM) {
            int g = batch[nc];
            scp = param + (size_t)g * 128 + k0;
            shp = param + (size_t)g * 128 + 64 + k0;
        }
        uint q[8];
#pragma unroll
        for (int j = 0; j < 8; ++j) {
            float a = v ? xrow[j * 2] : 0.f;
            float b = v ? xrow[j * 2 + 1] : 0.f;
            if constexpr (NORM) {
                a = fmaxf(fmaf(scp[j * 2], a, shp[j * 2]), 0.f);
                b = fmaxf(fmaf(scp[j * 2 + 1], b, shp[j * 2 + 1]), 0.f);
            }
            q[j] = pack_bf2(a, b);
        }
        char* base = (char*)Xs + nl * 128;
        uint sw = (uint)(nl & 7) << 4;
        *(uint4*)(base + (((uint)(k0 * 2)) ^ sw))      = make_uint4(q[0], q[1], q[2], q[3]);
        *(uint4*)(base + (((uint)(k0 * 2 + 16)) ^ sw)) = make_uint4(q[4], q[5], q[6], q[7]);
    }
    for (int ch = tid; ch < NCOLS * 8; ch += 256) {
        int col = ch >> 3, sub = ch & 7;
        uint4 q = ((const uint4*)(Wt + col * 64))[sub];
        *(uint4*)((char*)Ws + col * 128 + (((uint)(sub * 16)) ^ ((uint)(col & 7) << 4))) = q;
    }
    __syncthreads();

    int lane = tid & 63;
    int wv = tid >> 6;
    int l15 = lane & 15, quad = lane >> 4;

    bf16x8 xf[2];
    {
        int row = wv * 16 + l15;
        char* base = (char*)Xs + row * 128;
        uint sw = (uint)(row & 7) << 4;
        xf[0] = *(bf16x8*)(base + (((uint)(quad * 16)) ^ sw));
        xf[1] = *(bf16x8*)(base + (((uint)(64 + quad * 16)) ^ sw));
    }
    f32x4 acc[NT];
#pragma unroll
    for (int t = 0; t < NT; ++t) acc[t] = (f32x4){0.f, 0.f, 0.f, 0.f};
#pragma unroll
    for (int t = 0; t < NT; ++t) {
        int col = t * 16 + l15;
        char* base = (char*)Ws + col * 128;
        uint sw = (uint)(col & 7) << 4;
        bf16x8 a0 = *(bf16x8*)(base + (((uint)(quad * 16)) ^ sw));
        bf16x8 a1 = *(bf16x8*)(base + (((uint)(64 + quad * 16)) ^ sw));
        acc[t] = __builtin_amdgcn_mfma_f32_16x16x32_bf16(a0, xf[0], acc[t], 0, 0, 0);
        acc[t] = __builtin_amdgcn_mfma_f32_16x16x32_bf16(a1, xf[1], acc[t], 0, 0, 0);
    }
    int node = node0 + wv * 16 + l15;
    if (node < nN) {
#pragma unroll
        for (int t = 0; t < NT; ++t) {
            int cg = t * 16 + quad * 4;
            unsigned short* outp = (cg < OD) ? xl : xr;
            int ocol = (cg < OD) ? cg : cg - OD;
            uint2 pk;
            pk.x = pack_bf2(acc[t][0], acc[t][1]);
            pk.y = pack_bf2(acc[t][2], acc[t][3]);
            *(uint2*)(outp + (size_t)node * OD + ocol) = pk;
        }
    }
}

// ---------------- Aggregate layer 1-2: D=64, H=4, C=16, concat ----------------

__global__ void agg64_kernel(const unsigned short* __restrict__ xl, const unsigned short* __restrict__ xr,
                             const int* __restrict__ rowstart, const int* __restrict__ csr,
                             const float* __restrict__ att, const float* __restrict__ bias,
                             float* __restrict__ out, int nN) {
    int wid = (blockIdx.x * blockDim.x + threadIdx.x) >> 6;
    int lane = threadIdx.x & 63;
    if (wid >= nN) return;
    int c8 = lane & 7;
    int sg = lane >> 3;
    const uint4* xl4 = (const uint4*)xl;
    const float LOG2E = 1.4426950408889634f;
    float4 attA = ((const float4*)att)[c8 * 2];
    float4 attB = ((const float4*)att)[c8 * 2 + 1];
    attA.x *= LOG2E; attA.y *= LOG2E; attA.z *= LOG2E; attA.w *= LOG2E;
    attB.x *= LOG2E; attB.y *= LOG2E; attB.z *= LOG2E; attB.w *= LOG2E;
    uint4 xru = ((const uint4*)xr)[(size_t)wid * 8 + c8];
    float4 xrA = bf4(xru.x, xru.y), xrB = bf4(xru.z, xru.w);
    int rs = rowstart[wid], re = rowstart[wid + 1];
    int nIt = (re - rs + 7) >> 3;
    float den = 0.f;
    float4 accA = make_float4(0.f, 0.f, 0.f, 0.f);
    float4 accB = make_float4(0.f, 0.f, 0.f, 0.f);
    int i = rs + sg;
    int s = csr[i];
    uint4 xv = xl4[(size_t)s * 8 + c8];
    for (int it = 0; it < nIt; ++it) {
        float4 curA = bf4(xv.x, xv.y), curB = bf4(xv.z, xv.w);
        bool vv = i < re;
        i += 8;
        s = csr[i];
        xv = xl4[(size_t)s * 8 + c8];
        float4 mA, mB;
        mA.x = curA.x + xrA.x; mA.y = curA.y + xrA.y;
        mA.z = curA.z + xrA.z; mA.w = curA.w + xrA.w;
        mB.x = curB.x + xrB.x; mB.y = curB.y + xrB.y;
        mB.z = curB.z + xrB.z; mB.w = curB.w + xrB.w;
        mA.x = fmaxf(mA.x, LEAKY * mA.x); mA.y = fmaxf(mA.y, LEAKY * mA.y);
        mA.z = fmaxf(mA.z, LEAKY * mA.z); mA.w = fmaxf(mA.w, LEAKY * mA.w);
        mB.x = fmaxf(mB.x, LEAKY * mB.x); mB.y = fmaxf(mB.y, LEAKY * mB.y);
        mB.z = fmaxf(mB.z, LEAKY * mB.z); mB.w = fmaxf(mB.w, LEAKY * mB.w);
        float p = mA.x * attA.x;
        p = fmaf(mA.y, attA.y, p); p = fmaf(mA.z, attA.z, p); p = fmaf(mA.w, attA.w, p);
        p = fmaf(mB.x, attB.x, p); p = fmaf(mB.y, attB.y, p);
        p = fmaf(mB.z, attB.z, p); p = fmaf(mB.w, attB.w, p);
        p += __shfl_xor(p, 1);
        float w = vv ? exp2f(p) : 0.f;
        den += w;
        accA.x = fmaf(w, curA.x, accA.x); accA.y = fmaf(w, curA.y, accA.y);
        accA.z = fmaf(w, curA.z, accA.z); accA.w = fmaf(w, curA.w, accA.w);
        accB.x = fmaf(w, curB.x, accB.x); accB.y = fmaf(w, curB.y, accB.y);
        accB.z = fmaf(w, curB.z, accB.z); accB.w = fmaf(w, curB.w, accB.w);
    }
#pragma unroll
    for (int off = 8; off <= 32; off <<= 1) {
        den    += __shfl_xor(den, off);
        accA.x += __shfl_xor(accA.x, off); accA.y += __shfl_xor(accA.y, off);
        accA.z += __shfl_xor(accA.z, off); accA.w += __shfl_xor(accA.w, off);
        accB.x += __shfl_xor(accB.x, off); accB.y += __shfl_xor(accB.y, off);
        accB.z += __shfl_xor(accB.z, off); accB.w += __shfl_xor(accB.w, off);
    }
    if (lane < 8) {
        float4 bvA = ((const float4*)bias)[c8 * 2];
        float4 bvB = ((const float4*)bias)[c8 * 2 + 1];
        float inv = 1.f / den;
        float4 rA, rB;
        rA.x = fmaf(accA.x, inv, bvA.x); rA.y = fmaf(accA.y, inv, bvA.y);
        rA.z = fmaf(accA.z, inv, bvA.z); rA.w = fmaf(accA.w, inv, bvA.w);
        rB.x = fmaf(accB.x, inv, bvB.x); rB.y = fmaf(accB.y, inv, bvB.y);
        rB.z = fmaf(accB.z, inv, bvB.z); rB.w = fmaf(accB.w, inv, bvB.w);
        ((float4*)out)[(size_t)wid * 16 + c8 * 2]     = rA;
        ((float4*)out)[(size_t)wid * 16 + c8 * 2 + 1] = rB;
    }
}

// ---------------- Aggregate layer 3: D=128, H=4, C=32, head-mean ----------------

__global__ void agg128_mean_kernel(const unsigned short* __restrict__ xl, const unsigned short* __restrict__ xr,
                                   const int* __restrict__ rowstart, const int* __restrict__ csr,
                                   const float* __restrict__ att, const float* __restrict__ bias,
                                   float* __restrict__ out, int nN) {
    int wid = (blockIdx.x * blockDim.x + threadIdx.x) >> 6;
    int lane = threadIdx.x & 63;
    if (wid >= nN) return;
    int c8 = lane & 15;
    int sg = lane >> 4;
    const uint4* xl4 = (const uint4*)xl;
    const float LOG2E = 1.4426950408889634f;
    float4 attA = ((const float4*)att)[c8 * 2];
    float4 attB = ((const float4*)att)[c8 * 2 + 1];
    attA.x *= LOG2E; attA.y *= LOG2E; attA.z *= LOG2E; attA.w *= LOG2E;
    attB.x *= LOG2E; attB.y *= LOG2E; attB.z *= LOG2E; attB.w *= LOG2E;
    uint4 xru = ((const uint4*)xr)[(size_t)wid * 16 + c8];
    float4 xrA = bf4(xru.x, xru.y), xrB = bf4(xru.z, xru.w);
    int rs = rowstart[wid], re = rowstart[wid + 1];
    int nIt = (re - rs + 3) >> 2;
    float den = 0.f;
    float4 accA = make_float4(0.f, 0.f, 0.f, 0.f);
    float4 accB = make_float4(0.f, 0.f, 0.f, 0.f);
    int i = rs + sg;
    int s = csr[i];
    uint4 xv = xl4[(size_t)s * 16 + c8];
    for (int it = 0; it < nIt; ++it) {
        float4 curA = bf4(xv.x, xv.y), curB = bf4(xv.z, xv.w);
        bool vv = i < re;
        i += 4;
        s = csr[i];
        xv = xl4[(size_t)s * 16 + c8];
        float4 mA, mB;
        mA.x = curA.x + xrA.x; mA.y = curA.y + xrA.y;
        mA.z = curA.z + xrA.z; mA.w = curA.w + xrA.w;
        mB.x = curB.x + xrB.x; mB.y = curB.y + xrB.y;
        mB.z = curB.z + xrB.z; mB.w = curB.w + xrB.w;
        mA.x = fmaxf(mA.x, LEAKY * mA.x); mA.y = fmaxf(mA.y, LEAKY * mA.y);
        mA.z = fmaxf(mA.z, LEAKY * mA.z); mA.w = fmaxf(mA.w, LEAKY * mA.w);
        mB.x = fmaxf(mB.x, LEAKY * mB.x); mB.y = fmaxf(mB.y, LEAKY * mB.y);
        mB.z = fmaxf(mB.z, LEAKY * mB.z); mB.w = fmaxf(mB.w, LEAKY * mB.w);
        float p = mA.x * attA.x;
        p = fmaf(mA.y, attA.y, p); p = fmaf(mA.z, attA.z, p); p = fmaf(mA.w, attA.w, p);
        p = fmaf(mB.x, attB.x, p); p = fmaf(mB.y, attB.y, p);
        p = fmaf(mB.z, attB.z, p); p = fmaf(mB.w, attB.w, p);
        p += __shfl_xor(p, 1);
        p += __shfl_xor(p, 2);
        float w = vv ? exp2f(p) : 0.f;
        den += w;
        accA.x = fmaf(w, curA.x, accA.x); accA.y = fmaf(w, curA.y, accA.y);
        accA.z = fmaf(w, curA.z, accA.z); accA.w = fmaf(w, curA.w, accA.w);
        accB.x = fmaf(w, curB.x, accB.x); accB.y = fmaf(w, curB.y, accB.y);
        accB.z = fmaf(w, curB.z, accB.z); accB.w = fmaf(w, curB.w, accB.w);
    }
#pragma unroll
    for (int off = 16; off <= 32; off <<= 1) {
        den    += __shfl_xor(den, off);
        accA.x += __shfl_xor(accA.x, off); accA.y += __shfl_xor(accA.y, off);
        accA.z += __shfl_xor(accA.z, off); accA.w += __shfl_xor(accA.w, off);
        accB.x += __shfl_xor(accB.x, off); accB.y += __shfl_xor(accB.y, off);
        accB.z += __shfl_xor(accB.z, off); accB.w += __shfl_xor(accB.w, off);
    }
    float inv = 1.f / den;
    float4 rA, rB;
    rA.x = accA.x * inv; rA.y = accA.y * inv; rA.z = accA.z * inv; rA.w = accA.w * inv;
    rB.x = accB.x * inv; rB.y = accB.y * inv; rB.z = accB.z * inv; rB.w = accB.w * inv;
#pragma unroll
    for (int off = 4; off <= 8; off <<= 1) {
        rA.x += __shfl_xor(rA.x, off); rA.y += __shfl_xor(rA.y, off);
        rA.z += __shfl_xor(rA.z, off); rA.w += __shfl_xor(rA.w, off);
        rB.x += __shfl_xor(rB.x, off); rB.y += __shfl_xor(rB.y, off);
        rB.z += __shfl_xor(rB.z, off); rB.w += __shfl_xor(rB.w, off);
    }
    if (lane < 4) {
        float4 bvA = ((const float4*)bias)[lane * 2];
        float4 bvB = ((const float4*)bias)[lane * 2 + 1];
        float4 oA, oB;
        oA.x = fmaf(rA.x, 0.25f, bvA.x); oA.y = fmaf(rA.y, 0.25f, bvA.y);
        oA.z = fmaf(rA.z, 0.25f, bvA.z); oA.w = fmaf(rA.w, 0.25f, bvA.w);
        oB.x = fmaf(rB.x, 0.25f, bvB.x); oB.y = fmaf(rB.y, 0.25f, bvB.y);
        oB.z = fmaf(rB.z, 0.25f, bvB.z); oB.w = fmaf(rB.w, 0.25f, bvB.w);
        ((float4*)out)[(size_t)wid * 8 + lane * 2]     = oA;
        ((float4*)out)[(size_t)wid * 8 + lane * 2 + 1] = oB;
    }
}

// ---------------- GraphNorm stats / finalize ----------------

template <int D>
__global__ void gnorm_stats_kernel(const float* __restrict__ in, const int* __restrict__ goff,
                                   float* __restrict__ stats, int SPLIT) {
    int g = blockIdx.x / SPLIT, part = blockIdx.x % SPLIT;
    int start = goff[g], end = goff[g + 1];
    constexpr int RPB = 256 / D;
    int tid = threadIdx.x;
    int c = tid % D, sub = tid / D;
    float s1 = 0.f, s2 = 0.f;
    for (int n = start + part * RPB + sub; n < end; n += SPLIT * RPB) {
        float v = in[(size_t)n * D + c];
        s1 += v; s2 += v * v;
    }
    __shared__ float l1[256], l2[256];
    l1[tid] = s1; l2[tid] = s2;
    __syncthreads();
    if (tid < D) {
        for (int s = 1; s < RPB; ++s) { s1 += l1[s * D + tid]; s2 += l2[s * D + tid]; }
        atomicAdd(&stats[(size_t)g * 2 * D + tid], s1);
        atomicAdd(&stats[(size_t)g * 2 * D + D + tid], s2);
    }
}

template <int D>
__global__ void gnorm_finalize_kernel(const float* __restrict__ stats, const int* __restrict__ goff,
                                      const float* __restrict__ w, const float* __restrict__ b,
                                      const float* __restrict__ a, float* __restrict__ param) {
    int g = blockIdx.x, c = threadIdx.x;
    if (c >= D) return;
    int cn = goff[g + 1] - goff[g];
    float cnt = (float)(cn > 1 ? cn : 1);
    float S1 = stats[(size_t)g * 2 * D + c], S2 = stats[(size_t)g * 2 * D + D + c];
    float mu = S1 / cnt;
    float am = a[c] * mu;
    float var = S2 / cnt - 2.f * am * mu + am * am;
    float sc = w[c] * rsqrtf(var + EPS_GN);
    param[(size_t)g * 2 * D + c] = sc;
    param[(size_t)g * 2 * D + D + c] = b[c] - sc * am;
}

// ---------------- layer-3 tail ----------------

__global__ void pool3_kernel(const float* __restrict__ in, const int* __restrict__ goff,
                             const float* __restrict__ param, float* __restrict__ pooled, int SPLIT) {
    int g = blockIdx.x / SPLIT, part = blockIdx.x % SPLIT;
    int start = goff[g], end = goff[g + 1];
    int tid = threadIdx.x;
    int c = tid & 31, sub = tid >> 5;
    float sc = param[(size_t)g * 64 + c], sh = param[(size_t)g * 64 + 32 + c];
    float s = 0.f;
    for (int n = start + part * 8 + sub; n < end; n += SPLIT * 8)
        s += fmaxf(fmaf(sc, in[(size_t)n * 32 + c], sh), 0.f);
    __shared__ float l[256];
    l[tid] = s;
    __syncthreads();
    if (tid < 32) {
        for (int q = 1; q < 8; ++q) s += l[q * 32 + tid];
        atomicAdd(&pooled[(size_t)g * 32 + tid], s);
    }
}

__global__ void lin_kernel(const float* __restrict__ pooled, const int* __restrict__ goff,
                           const float* __restrict__ Wlin, const float* __restrict__ blin,
                           float* __restrict__ out, int nG) {
    int idx = blockIdx.x * blockDim.x + threadIdx.x;
    if (idx >= nG * 2) return;
    int g = idx >> 1, o = idx & 1;
    int cn = goff[g + 1] - goff[g];
    float inv = 1.f / (float)(cn > 1 ? cn : 1);
    float acc = blin[o];
    for (int c = 0; c < 32; ++c) acc = fmaf(pooled[(size_t)g * 32 + c] * inv, Wlin[c * 2 + o], acc);
    out[idx] = acc;
}

// ---------------- launch ----------------

extern "C" void kernel_launch(void* const* d_in, const int* in_sizes, int n_in,
                              void* d_out, int out_size, void* d_ws, size_t ws_size,
                              hipStream_t stream) {
    const float* x    = (const float*)d_in[0];
    const int*  eidx  = (const int*)d_in[1];
    const int*  batch = (const int*)d_in[2];
    const float* Wl1 = (const float*)d_in[3];
    const float* Wr1 = (const float*)d_in[4];
    const float* att1 = (const float*)d_in[5];
    const float* b1 = (const float*)d_in[6];
    const float* g1w = (const float*)d_in[7];
    const float* g1b = (const float*)d_in[8];
    const float* g1a = (const float*)d_in[9];
    const float* Wl2 = (const float*)d_in[10];
    const float* Wr2 = (const float*)d_in[11];
    const float* att2 = (const float*)d_in[12];
    const float* b2 = (const float*)d_in[13];
    const float* g2w = (const float*)d_in[14];
    const float* g2b = (const float*)d_in[15];
    const float* g2a = (const float*)d_in[16];
    const float* Wl3 = (const float*)d_in[17];
    const float* Wr3 = (const float*)d_in[18];
    const float* att3 = (const float*)d_in[19];
    const float* b3 = (const float*)d_in[20];
    const float* g3w = (const float*)d_in[21];
    const float* g3b = (const float*)d_in[22];
    const float* g3a = (const float*)d_in[23];
    const float* Wlin = (const float*)d_in[24];
    const float* blin = (const float*)d_in[25];
    float* outp = (float*)d_out;

    const int N = in_sizes[0] / 64;
    const int E = in_sizes[1] / 2;
    const int Etot = N + E;
    const int G = out_size / 2;
    const int P = (N + (1 << PSH) - 1) >> PSH;
    const int SPLIT = 16;

    unsigned short* xlb = (unsigned short*)d_ws;           // N*128 bf16
    unsigned short* xrb = xlb + (size_t)N * 128;           // N*128 bf16
    float* agg   = (float*)(xrb + (size_t)N * 128);        // N*64 f32
    float* stats = agg + (size_t)N * 64;                   // G*352 (stats1/2/3 + pooled)
    float* stats1 = stats;
    float* stats2 = stats1 + (size_t)G * 128;
    float* stats3 = stats2 + (size_t)G * 128;
    float* pooled = stats3 + (size_t)G * 64;
    float* param  = pooled + (size_t)G * 32;               // G*128, reused per layer
    int* rowstart = (int*)(param + (size_t)G * 128);       // N+1
    int* csr      = rowstart + (N + 1);                    // Etot + 16 pad
    uint* ebuf    = (uint*)(csr + Etot + 16);              // Etot
    int* goff     = (int*)(ebuf + Etot);                   // G+1
    int* gcur     = goff + (G + 1);                        // 257
    int* pstart   = gcur + 257;                            // 257
    int* pcnt     = pstart + 257;                          // 256
    unsigned short* wt1 = (unsigned short*)(pcnt + 256);   // 128*64 bf16
    unsigned short* wt2 = wt1 + 8192;                      // 128*64
    unsigned short* wt3 = wt2 + 8192;                      // 256*64

    const int* src_idx = eidx;
    const int* dst_idx = eidx + E;

    const int statN = G * 352;
    int setupTotal = statN + 32768 + 256 + 16 + (G + 1);
    setup_kernel<<<(setupTotal + 255) / 256, 256, 0, stream>>>(
        stats, statN, Wl1, Wr1, Wl2, Wr2, Wl3, Wr3, wt1, wt2, wt3,
        pcnt, csr + Etot, batch, goff, N, G);

    int edgeBlocks = (Etot + 2047) / 2048;
    pcount_kernel<<<edgeBlocks, 256, 0, stream>>>(dst_idx, pcnt, E, Etot);
    pscan_kernel<<<1, 256, 0, stream>>>(pcnt, pstart, gcur, rowstart, N);
    partA_kernel<<<edgeBlocks, 256, 0, stream>>>(src_idx, dst_idx, gcur, ebuf, E, Etot);
    partB2_kernel<<<P, 256, 0, stream>>>(ebuf, pstart, rowstart, csr, N);

    dim3 blk(256);
    int aggGrid = (N + 3) / 4;
    int gemmGrid = (N + 63) / 64;

    // Layer 1
    gemm_mfma_kernel<128, false><<<gemmGrid, blk, 0, stream>>>(x, wt1, xlb, xrb, N, nullptr, nullptr);
    agg64_kernel<<<aggGrid, blk, 0, stream>>>(xlb, xrb, rowstart, csr, att1, b1, agg, N);
    gnorm_stats_kernel<64><<<G * SPLIT, blk, 0, stream>>>(agg, goff, stats1, SPLIT);
    gnorm_finalize_kernel<64><<<G, 64, 0, stream>>>(stats1, goff, g1w, g1b, g1a, param);

    // Layer 2 (norm fused into GEMM X-staging)
    gemm_mfma_kernel<128, true><<<gemmGrid, blk, 0, stream>>>(agg, wt2, xlb, xrb, N, param, batch);
    agg64_kernel<<<aggGrid, blk, 0, stream>>>(xlb, xrb, rowstart, csr, att2, b2, agg, N);
    gnorm_stats_kernel<64><<<G * SPLIT, blk, 0, stream>>>(agg, goff, stats2, SPLIT);
    gnorm_finalize_kernel<64><<<G, 64, 0, stream>>>(stats2, goff, g2w, g2b, g2a, param);

    // Layer 3 (norm fused into GEMM X-staging; 256 fused cols)
    gemm_mfma_kernel<256, true><<<gemmGrid, blk, 0, stream>>>(agg, wt3, xlb, xrb, N, param, batch);
    agg128_mean_kernel<<<aggGrid, blk, 0, stream>>>(xlb, xrb, rowstart, csr, att3, b3, agg, N);
    gnorm_stats_kernel<32><<<G * SPLIT, blk, 0, stream>>>(agg, goff, stats3, SPLIT);
    gnorm_finalize_kernel<32><<<G, 32, 0, stream>>>(stats3, goff, g3w, g3b, g3a, param);
    pool3_kernel<<<G * SPLIT, blk, 0, stream>>>(agg, goff, param, pooled, SPLIT);
    lin_kernel<<<(G * 2 + 63) / 64, 64, 0, stream>>>(pooled, goff, Wlin, blin, outp, G);
}